// Round 9
// baseline (223.916 us; speedup 1.0000x reference)
//
#include <hip/hip_runtime.h>

#define QLEN 512
#define MLEN 512
#define KLEN 1024
#define BB   8
#define DMODEL 1024
#define NH   16
#define HD   64
#define NF   384
#define ATT_SCALE 0.125f
#define EPSV 1e-5f

typedef float v4f __attribute__((ext_vector_type(4)));
typedef float f32x16 __attribute__((ext_vector_type(16)));
typedef short bf16x8 __attribute__((ext_vector_type(8)));
typedef unsigned int u32x4 __attribute__((ext_vector_type(4)));
typedef unsigned int u32x2 __attribute__((ext_vector_type(2)));
typedef unsigned short u16x8 __attribute__((ext_vector_type(8)));

__device__ __forceinline__ unsigned short f2bf(float f) {
    unsigned int x = __builtin_bit_cast(unsigned int, f);
    x += 0x7fffu + ((x >> 16) & 1u);
    return (unsigned short)(x >> 16);
}

__device__ __forceinline__ void gll16(const void* g, void* l) {
    __builtin_amdgcn_global_load_lds(
        (const __attribute__((address_space(1))) unsigned int*)g,
        (__attribute__((address_space(3))) unsigned int*)l, 16, 0, 0);
}

// ---------------------------------------------------------------------------
// Fused f32->bf16 converts: mems+h -> cbf (c matrix), weights -> bf16 scratch
// ---------------------------------------------------------------------------
__global__ __launch_bounds__(256)
void cvt_all_kernel(const float* __restrict__ h, const float* __restrict__ mems,
                    const float* __restrict__ Wq, const float* __restrict__ Wkv,
                    const float* __restrict__ Wo,
                    unsigned short* __restrict__ cbf, unsigned short* __restrict__ wqb,
                    unsigned short* __restrict__ wkvb, unsigned short* __restrict__ wob)
{
    int blk = blockIdx.x;
    const float* src; unsigned short* dst; int base;
    if (blk < 4096)       { src = mems; dst = cbf;           base = blk; }
    else if (blk < 8192)  { src = h;    dst = cbf + 4194304; base = blk - 4096; }
    else if (blk < 9216)  { src = Wq;   dst = wqb;           base = blk - 8192; }
    else if (blk < 11264) { src = Wkv;  dst = wkvb;          base = blk - 9216; }
    else                  { src = Wo;   dst = wob;           base = blk - 11264; }
    int i = (base * 256 + threadIdx.x) * 4;
    v4f v = *(const v4f*)(src + i);
    unsigned int p0, p1;
    asm("v_cvt_pk_bf16_f32 %0, %1, %2" : "=v"(p0) : "v"(v[0]), "v"(v[1]));
    asm("v_cvt_pk_bf16_f32 %0, %1, %2" : "=v"(p1) : "v"(v[2]), "v"(v[3]));
    uint2 u; u.x = p0; u.y = p1;
    *(uint2*)(dst + i) = u;
}

// ---------------------------------------------------------------------------
// Pure MFMA GEMM, 128x128 tile, BK=64, 4 waves (each 64x64 = 4x4 frags).
// MODE 0: out = q_raw bf16; MODE 1: outK/outV = k_raw/v_raw bf16;
// MODE 2: xo f32 = C + hres
// ---------------------------------------------------------------------------
template<int MODE>
__global__ __launch_bounds__(256)
void mm128_kernel(const unsigned short* __restrict__ Abf,
                  const unsigned short* __restrict__ Bbf,
                  const float* __restrict__ hres,
                  unsigned short* __restrict__ outK,
                  unsigned short* __restrict__ outV,
                  float* __restrict__ xo)
{
    __shared__ unsigned short As[128 * 64];
    __shared__ unsigned short Bs[128 * 64];

    const int t  = threadIdx.x;
    const int w  = t >> 6;
    const int l  = t & 63;
    const int lj = l & 15;
    const int lg = l >> 4;
    const int m0 = blockIdx.x * 128;
    const int n0 = blockIdx.y * 128;
    const int wr = w >> 1, wc = w & 1;
    const int rsub = l >> 3;
    const int csw  = ((l & 7) ^ rsub) * 16;

    v4f acc[4][4] = {};

    for (int s = 0; s < 16; ++s) {
        const int k0b = s * 128;
        __syncthreads();
        #pragma unroll
        for (int u = 0; u < 4; ++u) {
            int ra = w * 32 + u * 8;
            gll16((const char*)Abf + (size_t)(m0 + ra + rsub) * 2048 + k0b + csw,
                  (char*)As + ra * 128);
            gll16((const char*)Bbf + (size_t)(n0 + ra + rsub) * 2048 + k0b + csw,
                  (char*)Bs + ra * 128);
        }
        __syncthreads();
        #pragma unroll
        for (int ks = 0; ks < 2; ++ks) {
            bf16x8 af[4], bfr[4];
            #pragma unroll
            for (int m = 0; m < 4; ++m) {
                int row = wr * 64 + m * 16 + lj;
                int c = ks * 4 + lg;
                af[m] = *(const bf16x8*)((const char*)As + row * 128 +
                                         ((c ^ (row & 7)) * 16));
            }
            #pragma unroll
            for (int nn = 0; nn < 4; ++nn) {
                int row = wc * 64 + nn * 16 + lj;
                int c = ks * 4 + lg;
                bfr[nn] = *(const bf16x8*)((const char*)Bs + row * 128 +
                                           ((c ^ (row & 7)) * 16));
            }
            #pragma unroll
            for (int m = 0; m < 4; ++m)
                #pragma unroll
                for (int nn = 0; nn < 4; ++nn)
                    acc[m][nn] = __builtin_amdgcn_mfma_f32_16x16x32_bf16(
                                     af[m], bfr[nn], acc[m][nn], 0, 0, 0);
        }
    }

    #pragma unroll
    for (int m = 0; m < 4; ++m) {
        #pragma unroll
        for (int rr = 0; rr < 4; ++rr) {
            int row = m0 + wr * 64 + m * 16 + 4 * lg + rr;
            #pragma unroll
            for (int nn = 0; nn < 4; ++nn) {
                int col = n0 + wc * 64 + nn * 16 + lj;
                float v = acc[m][nn][rr];
                if constexpr (MODE == 2) {
                    xo[(size_t)row * 1024 + col] = v + hres[(size_t)row * 1024 + col];
                } else if constexpr (MODE == 0) {
                    outK[(size_t)row * 1024 + col] = f2bf(v);
                } else {
                    if (n0 < 1024) outK[(size_t)row * 1024 + col] = f2bf(v);
                    else           outV[(size_t)row * 1024 + (col - 1024)] = f2bf(v);
                }
            }
        }
    }
}

// ---------------------------------------------------------------------------
// DPFP feature kernel — LDS-resident g. Output chunk-blocked:
//   feat[bh][rb][c48][row64][e8]
// ---------------------------------------------------------------------------
__device__ __forceinline__ float gld(const unsigned short* gr, int idx) {
    return __builtin_bit_cast(float, ((unsigned int)gr[idx]) << 16);
}

template<int FBASE>
__device__ __forceinline__ void dpfp_half(const unsigned short* __restrict__ gr,
                                          unsigned short* __restrict__ drow)
{
    #pragma unroll
    for (int c = 0; c < 24; ++c) {
        unsigned int w4[4];
        #pragma unroll
        for (int q2 = 0; q2 < 4; ++q2) {
            const int f  = FBASE + c * 8 + q2 * 2;
            const int r0 = (f >> 7) + 1,       t0 = f & 127,       u0 = (t0 - r0) & 127;
            const int f1 = f + 1;
            const int r1 = (f1 >> 7) + 1,      t1 = f1 & 127,      u1 = (t1 - r1) & 127;
            float p0 = gld(gr, t0) * gld(gr, u0);
            float p1 = gld(gr, t1) * gld(gr, u1);
            asm("v_cvt_pk_bf16_f32 %0, %1, %2" : "=v"(w4[q2]) : "v"(p0), "v"(p1));
        }
        u32x4 st = {w4[0], w4[1], w4[2], w4[3]};
        *(u32x4*)(drow + c * 512) = st;
    }
}

__global__ __launch_bounds__(256)
void dpfp_kernel(const unsigned short* __restrict__ qraw,
                 const unsigned short* __restrict__ kraw,
                 unsigned short* __restrict__ qf, unsigned short* __restrict__ kf)
{
    __shared__ unsigned short G[128 * 138];

    const int t   = threadIdx.x;
    const int blk = blockIdx.x;

    const unsigned short* src; unsigned short* dst; int b, hh, seq0;
    if (blk < 512) {
        int bh = blk >> 2, ig = blk & 3;
        b = bh >> 4; hh = bh & 15; seq0 = ig * 128;
        src = qraw; dst = qf + (size_t)bh * (QLEN * NF);
    } else {
        int blk2 = blk - 512;
        int bh = blk2 >> 3, jg = blk2 & 7;
        b = bh >> 4; hh = bh & 15; seq0 = jg * 128;
        src = kraw; dst = kf + (size_t)bh * (KLEN * NF);
    }

    #pragma unroll
    for (int p = 0; p < 4; ++p) {
        int u   = p * 256 + t;
        int row = u >> 3;
        int c0  = (u & 7) * 8;
        u32x4 x = *(const u32x4*)(src + ((size_t)(seq0 + row) * 8 + b) * 1024 +
                                  hh * 64 + c0);
        char* gbase = (char*)G + row * 276 + c0 * 2;
        #pragma unroll
        for (int k = 0; k < 4; ++k) {
            unsigned int xk = x[k];
            float x0 = __builtin_bit_cast(float, xk << 16);
            float x1 = __builtin_bit_cast(float, xk & 0xffff0000u);
            float a0 = fmaxf(x0, 0.f), a1 = fmaxf(x1, 0.f);
            float b0 = fmaxf(-x0, 0.f), b1 = fmaxf(-x1, 0.f);
            unsigned int lo, hig;
            asm("v_cvt_pk_bf16_f32 %0, %1, %2" : "=v"(lo) : "v"(a0), "v"(a1));
            asm("v_cvt_pk_bf16_f32 %0, %1, %2" : "=v"(hig) : "v"(b0), "v"(b1));
            *(unsigned int*)(gbase + k * 4)       = lo;
            *(unsigned int*)(gbase + 128 + k * 4) = hig;
        }
    }
    __syncthreads();

    const int w    = t >> 6;
    const int l    = t & 63;
    const int rowc = (w >> 1) * 64 + l;
    const int hs   = w & 1;
    const unsigned short* gr = G + rowc * 138;
    const int seq = seq0 + rowc;
    unsigned short* drow = dst + (size_t)(seq >> 6) * (64 * NF) + (seq & 63) * 8 +
                           hs * (24 * 512);
    if (hs == 0) dpfp_half<0>(gr, drow);
    else         dpfp_half<192>(gr, drow);
}

// ---------------------------------------------------------------------------
// V transpose: v_raw [8192=(j,b)][1024=(h,d)] bf16 -> vt [b,h][d][KLEN] bf16.
// ---------------------------------------------------------------------------
__global__ __launch_bounds__(256)
void vtrans_kernel(const unsigned short* __restrict__ vraw,
                   unsigned short* __restrict__ vt)
{
    __shared__ unsigned short S[256][72];
    const int t  = threadIdx.x;
    const int jc = blockIdx.x, hh = blockIdx.y, b = blockIdx.z;
    const unsigned short* src = vraw + (size_t)((jc * 256 + t) * 8 + b) * 1024 + hh * 64;
    #pragma unroll
    for (int c = 0; c < 8; ++c)
        *(u32x4*)&S[t][c * 8] = *(const u32x4*)(src + c * 8);
    __syncthreads();
    const int d = t >> 2, qq = t & 3;
    unsigned short* dst = vt + ((size_t)(b * NH + hh) * HD + d) * KLEN + jc * 256 + qq * 64;
    #pragma unroll
    for (int c8 = 0; c8 < 8; ++c8) {
        u16x8 o;
        #pragma unroll
        for (int e = 0; e < 8; ++e) o[e] = S[qq * 64 + c8 * 8 + e][d];
        *(u16x8*)(dst + c8 * 8) = o;
    }
}

// ---------------------------------------------------------------------------
// MFMA attention v3: 32x32 MFMA, swapped QK^T, in-register P (T12), and a
// 2-phase double-buffered K/V pipeline (T3/T4 minimum): KVBLK=32, raw
// s_barrier + manual vmcnt placed AFTER compute so staging latency hides
// under the MFMA/ds_read phase. LDS: 2x(24KB K + 4KB V) = 56KB, 2 blocks/CU.
// ---------------------------------------------------------------------------
__global__ __launch_bounds__(256, 2)
void attn_mfma_kernel(const unsigned short* __restrict__ qf,
                      const unsigned short* __restrict__ kf,
                      const unsigned short* __restrict__ vt,
                      unsigned short* __restrict__ avec)
{
    __shared__ unsigned short Ks[2][32 * 384];   // 24KB each: rows 768B, chunk^row&7
    __shared__ unsigned short Vs[2][64 * 32];    // 4KB each: rows(d) 64B, jc^(d&3)
    __shared__ float Ds[4][32];

    const int t  = threadIdx.x;
    const int w  = t >> 6;
    const int l  = t & 63;
    const int li = l & 31;
    const int hi = l >> 5;

    const int bid = blockIdx.x;
    const int it  = (bid >> 3) & 3;
    const int P   = ((bid >> 5) << 3) + (bid & 7);
    const int n   = P & 15;
    const int b   = P >> 4;

    const unsigned short* qpan = qf + (size_t)P * (QLEN * NF);
    const char* kpan = (const char*)(kf + (size_t)P * (KLEN * NF));
    const char* vpan = (const char*)(vt + (size_t)P * HD * KLEN);

    // K staging source offsets (6 x 1KB slices per wave, inverse-swizzled)
    int koff[6];
    #pragma unroll
    for (int u = 0; u < 6; ++u) {
        int S16  = (w * 6 + u) * 64 + l;          // 0..1535
        int rloc = S16 / 48;
        int c    = S16 - rloc * 48;
        int cg   = (c & ~7) | ((c & 7) ^ (rloc & 7));
        koff[u]  = cg * 1024 + rloc * 16;         // + (jt>>1)*49152 + (jt&1)*512
    }
    int voffb;
    {
        int s  = w * 64 + l;                      // 0..255
        int d  = s >> 2;
        int jc = s & 3;
        int jg = jc ^ (d & 3);
        voffb  = d * 2048 + jg * 16;              // + jt*64
    }

    // Q fragments (B operand): lane(col=i=li, k=8*hi+e), 24 k-slices
    bf16x8 qfr[24];
    {
        const unsigned short* qb = qpan + (size_t)(it * 2 + (w >> 1)) * (64 * NF)
                                   + ((w & 1) * 32 + li) * 8;
        #pragma unroll
        for (int ks = 0; ks < 24; ++ks)
            qfr[ks] = *(const bf16x8*)(qb + (ks * 2 + hi) * 512);
    }

    f32x16 num[2] = {};
    float den_acc = 0.f;

    const int ig         = it * 128 + w * 32 + li;  // this lane's i (S-col)
    const int my_jt_end  = it * 4 + 16 + w;
    const int jt_blk_end = it * 4 + 19;

    // ---- prologue: stage tile 0, drain, sync ----
    {
        const char* kt = kpan;
        #pragma unroll
        for (int u = 0; u < 6; ++u)
            gll16(kt + koff[u], (char*)Ks[0] + (w * 6 + u) * 1024);
        gll16(vpan + voffb, (char*)Vs[0] + w * 1024);
    }
    asm volatile("s_waitcnt vmcnt(0)" ::: "memory");
    __builtin_amdgcn_s_barrier();

    for (int jt = 0; ; ++jt) {
        const int cur   = jt & 1;
        const bool more = (jt < jt_blk_end);

        // ---- issue stage for jt+1 into the other buffer ----
        if (more) {
            const int jn = jt + 1;
            const char* kt = kpan + (size_t)(jn >> 1) * 49152 + (jn & 1) * 512;
            #pragma unroll
            for (int u = 0; u < 6; ++u)
                gll16(kt + koff[u], (char*)Ks[cur ^ 1] + (w * 6 + u) * 1024);
            gll16(vpan + jn * 64 + voffb, (char*)Vs[cur ^ 1] + w * 1024);
        }

        if (jt <= my_jt_end) {
            // ---- S^T = K·Q (32 j-rows) ----
            f32x16 sacc = {};
            #pragma unroll
            for (int ks = 0; ks < 24; ++ks) {
                int c  = ks * 2 + hi;
                int cs = (c & ~7) | ((c & 7) ^ (li & 7));
                bf16x8 kfr = *(const bf16x8*)((const char*)Ks[cur] + li * 768 + cs * 16);
                sacc = __builtin_amdgcn_mfma_f32_32x32x16_bf16(kfr, qfr[ks], sacc, 0, 0, 0);
            }

            // ---- causal mask on the diagonal tile ----
            if (jt == my_jt_end) {
                const int joff = jt * 32 - MLEN + 4 * hi;
                #pragma unroll
                for (int reg = 0; reg < 16; ++reg) {
                    int jr = (reg & 3) + 8 * (reg >> 2);
                    if (joff + jr > ig) sacc[reg] = 0.f;
                }
            }
            // ---- den accumulate ----
            {
                float dpart = 0.f;
                #pragma unroll
                for (int reg = 0; reg < 16; ++reg) dpart += sacc[reg];
                den_acc += dpart + __shfl_xor(dpart, 32);
            }

            // ---- P -> bf16 A-frags (cvt_pk + permlane32_swap), PV MFMA ----
            unsigned int c01, c23, c45, c67, c89, cab, ccd, cef;
            asm("v_cvt_pk_bf16_f32 %0, %1, %2" : "=v"(c01) : "v"(sacc[0]),  "v"(sacc[1]));
            asm("v_cvt_pk_bf16_f32 %0, %1, %2" : "=v"(c23) : "v"(sacc[2]),  "v"(sacc[3]));
            asm("v_cvt_pk_bf16_f32 %0, %1, %2" : "=v"(c45) : "v"(sacc[4]),  "v"(sacc[5]));
            asm("v_cvt_pk_bf16_f32 %0, %1, %2" : "=v"(c67) : "v"(sacc[6]),  "v"(sacc[7]));
            asm("v_cvt_pk_bf16_f32 %0, %1, %2" : "=v"(c89) : "v"(sacc[8]),  "v"(sacc[9]));
            asm("v_cvt_pk_bf16_f32 %0, %1, %2" : "=v"(cab) : "v"(sacc[10]), "v"(sacc[11]));
            asm("v_cvt_pk_bf16_f32 %0, %1, %2" : "=v"(ccd) : "v"(sacc[12]), "v"(sacc[13]));
            asm("v_cvt_pk_bf16_f32 %0, %1, %2" : "=v"(cef) : "v"(sacc[14]), "v"(sacc[15]));
            u32x2 r0 = __builtin_amdgcn_permlane32_swap(c01, c45, false, false);
            u32x2 r1 = __builtin_amdgcn_permlane32_swap(c23, c67, false, false);
            u32x2 r2 = __builtin_amdgcn_permlane32_swap(c89, ccd, false, false);
            u32x2 r3 = __builtin_amdgcn_permlane32_swap(cab, cef, false, false);
            u32x4 pw0 = {r0.x, r1.x, r0.y, r1.y};   // j = kk0*16 + 8hi + e
            u32x4 pw1 = {r2.x, r3.x, r2.y, r3.y};   // kk=1
            bf16x8 pa0 = __builtin_bit_cast(bf16x8, pw0);
            bf16x8 pa1 = __builtin_bit_cast(bf16x8, pw1);
            #pragma unroll
            for (int dd = 0; dd < 2; ++dd) {
                int d = dd * 32 + li;
                {
                    int js = hi ^ (d & 3);
                    bf16x8 vb = *(const bf16x8*)((const char*)Vs[cur] + d * 64 + js * 16);
                    num[dd] = __builtin_amdgcn_mfma_f32_32x32x16_bf16(pa0, vb, num[dd], 0, 0, 0);
                }
                {
                    int js = (2 + hi) ^ (d & 3);
                    bf16x8 vb = *(const bf16x8*)((const char*)Vs[cur] + d * 64 + js * 16);
                    num[dd] = __builtin_amdgcn_mfma_f32_32x32x16_bf16(pa1, vb, num[dd], 0, 0, 0);
                }
            }
        }

        if (!more) break;
        // next tile's loads have flown under the compute; drain + sync
        asm volatile("s_waitcnt vmcnt(0)" ::: "memory");
        __builtin_amdgcn_s_barrier();
    }

    // ---- den broadcast via tiny per-wave LDS, normalize, store bf16 ----
    if (l < 32) Ds[w][l] = den_acc;
    #pragma unroll
    for (int reg = 0; reg < 16; ++reg) {
        int i_loc = (reg & 3) + 8 * (reg >> 2) + 4 * hi;
        float dv = Ds[w][i_loc];
        float minv = ATT_SCALE / (dv * ATT_SCALE + EPSV);
        int ig2 = it * 128 + w * 32 + i_loc;
        unsigned short* orow = avec + ((size_t)ig2 * BB + b) * DMODEL + n * HD;
        orow[li]      = f2bf(num[0][reg] * minv);
        orow[32 + li] = f2bf(num[1][reg] * minv);
    }
}

// ---------------------------------------------------------------------------
// Row LayerNorm over DM=1024.
// ---------------------------------------------------------------------------
__global__ __launch_bounds__(256)
void ln_kernel(const float* __restrict__ x, const float* __restrict__ gamma,
               const float* __restrict__ beta, float* __restrict__ out)
{
    const int row = blockIdx.x;
    const int t = threadIdx.x;
    const float* xr = x + (size_t)row * DMODEL;
    v4f xv = *(const v4f*)(xr + (t << 2));
    float s1 = xv[0] + xv[1] + xv[2] + xv[3];
    float s2 = xv[0]*xv[0] + xv[1]*xv[1] + xv[2]*xv[2] + xv[3]*xv[3];
    #pragma unroll
    for (int off = 32; off > 0; off >>= 1) {
        s1 += __shfl_down(s1, off);
        s2 += __shfl_down(s2, off);
    }
    __shared__ float red[2][4];
    __shared__ float mv[2];
    const int wave = t >> 6;
    if ((t & 63) == 0) { red[0][wave] = s1; red[1][wave] = s2; }
    __syncthreads();
    if (t == 0) {
        float a = red[0][0] + red[0][1] + red[0][2] + red[0][3];
        float q = red[1][0] + red[1][1] + red[1][2] + red[1][3];
        float mu  = a * (1.f / DMODEL);
        float var = q * (1.f / DMODEL) - mu * mu;
        mv[0] = mu;
        mv[1] = rsqrtf(var + EPSV);
    }
    __syncthreads();
    float mu = mv[0], rs = mv[1];
    v4f gv = *(const v4f*)(gamma + (t << 2));
    v4f bv = *(const v4f*)(beta + (t << 2));
    v4f o;
    #pragma unroll
    for (int e = 0; e < 4; ++e) o[e] = (xv[e] - mu) * rs * gv[e] + bv[e];
    *(v4f*)(out + (size_t)row * DMODEL + (t << 2)) = o;
}

extern "C" void kernel_launch(void* const* d_in, const int* in_sizes, int n_in,
                              void* d_out, int out_size, void* d_ws, size_t ws_size,
                              hipStream_t stream)
{
    const float* h     = (const float*)d_in[0];
    const float* mems  = (const float*)d_in[1];
    const float* Wq    = (const float*)d_in[2];
    const float* Wkv   = (const float*)d_in[3];
    const float* Wo    = (const float*)d_in[4];
    const float* gamma = (const float*)d_in[5];
    const float* beta  = (const float*)d_in[6];
    // d_in[7] = attn_mask: causal structure computed analytically, ignored.

    char* ws = (char*)d_ws;
    unsigned short* qf   = (unsigned short*)(ws);             // [0, 50.33M)
    unsigned short* kf   = (unsigned short*)(ws + 50331648);  // [50.33M, 151.0M)
    unsigned short* kraw = (unsigned short*)(ws + 150994944); // 16.78M
    unsigned short* vt   = kraw;                              // overlay after dpfp
    unsigned short* vraw = (unsigned short*)(ws + 167772160); // 16.78M
    unsigned short* cbf  = (unsigned short*)(ws + 184549376); // 16.78M
    unsigned short* qraw = cbf;                               // overlay mems-half after mm1
    unsigned short* avec = cbf;                               // overlay after dpfp
    float* xws = (float*)(ws);                                // overlay qf after attn

    unsigned short* wqb  = (unsigned short*)d_out;            // bf16 weights in d_out
    unsigned short* wkvb = wqb + 1048576;
    unsigned short* wob  = wkvb + 2097152;

    cvt_all_kernel<<<12288, 256, 0, stream>>>(h, mems, Wq, Wkv, Wo, cbf, wqb, wkvb, wob);
    mm128_kernel<1><<<dim3(64, 16), 256, 0, stream>>>(cbf, wkvb, nullptr, kraw, vraw, nullptr);
    mm128_kernel<0><<<dim3(32, 8), 256, 0, stream>>>(cbf + 4194304, wqb, nullptr, qraw, nullptr, nullptr);
    dpfp_kernel<<<1536, 256, 0, stream>>>(qraw, kraw, qf, kf);
    vtrans_kernel<<<dim3(4, 16, 8), 256, 0, stream>>>(vraw, vt);
    attn_mfma_kernel<<<512, 256, 0, stream>>>(qf, kf, vt, avec);
    mm128_kernel<2><<<dim3(32, 8), 256, 0, stream>>>(avec, wob, h, nullptr, nullptr, xws);
    ln_kernel<<<4096, 256, 0, stream>>>(xws, gamma, beta, (float*)d_out);
}

// Round 10
// 190.556 us; speedup vs baseline: 1.1751x; 1.1751x over previous
//
#include <hip/hip_runtime.h>

#define QLEN 512
#define MLEN 512
#define KLEN 1024
#define BB   8
#define DMODEL 1024
#define NH   16
#define HD   64
#define NF   384
#define ATT_SCALE 0.125f
#define EPSV 1e-5f

typedef float v4f __attribute__((ext_vector_type(4)));
typedef float f32x16 __attribute__((ext_vector_type(16)));
typedef short bf16x8 __attribute__((ext_vector_type(8)));
typedef unsigned int u32x4 __attribute__((ext_vector_type(4)));
typedef unsigned int u32x2 __attribute__((ext_vector_type(2)));
typedef unsigned short u16x8 __attribute__((ext_vector_type(8)));

__device__ __forceinline__ unsigned short f2bf(float f) {
    unsigned int x = __builtin_bit_cast(unsigned int, f);
    x += 0x7fffu + ((x >> 16) & 1u);
    return (unsigned short)(x >> 16);
}

__device__ __forceinline__ void gll16(const void* g, void* l) {
    __builtin_amdgcn_global_load_lds(
        (const __attribute__((address_space(1))) unsigned int*)g,
        (__attribute__((address_space(3))) unsigned int*)l, 16, 0, 0);
}

// fp8 feature layout (bytes): feat[bh][rb][cell:24][row:64][16 fp8]
//   per (bh,rb): 24*1024 = 24576 B; q: 8 rb (196608 B/panel); k: 16 rb (393216)

// ---------------------------------------------------------------------------
// Fused f32->bf16 converts: mems+h -> cbf (c matrix), weights -> bf16 scratch
// ---------------------------------------------------------------------------
__global__ __launch_bounds__(256)
void cvt_all_kernel(const float* __restrict__ h, const float* __restrict__ mems,
                    const float* __restrict__ Wq, const float* __restrict__ Wkv,
                    const float* __restrict__ Wo,
                    unsigned short* __restrict__ cbf, unsigned short* __restrict__ wqb,
                    unsigned short* __restrict__ wkvb, unsigned short* __restrict__ wob)
{
    int blk = blockIdx.x;
    const float* src; unsigned short* dst; int base;
    if (blk < 4096)       { src = mems; dst = cbf;           base = blk; }
    else if (blk < 8192)  { src = h;    dst = cbf + 4194304; base = blk - 4096; }
    else if (blk < 9216)  { src = Wq;   dst = wqb;           base = blk - 8192; }
    else if (blk < 11264) { src = Wkv;  dst = wkvb;          base = blk - 9216; }
    else                  { src = Wo;   dst = wob;           base = blk - 11264; }
    int i = (base * 256 + threadIdx.x) * 4;
    v4f v = *(const v4f*)(src + i);
    unsigned int p0, p1;
    asm("v_cvt_pk_bf16_f32 %0, %1, %2" : "=v"(p0) : "v"(v[0]), "v"(v[1]));
    asm("v_cvt_pk_bf16_f32 %0, %1, %2" : "=v"(p1) : "v"(v[2]), "v"(v[3]));
    uint2 u; u.x = p0; u.y = p1;
    *(uint2*)(dst + i) = u;
}

// ---------------------------------------------------------------------------
// Pure MFMA GEMM, 128x128 tile, BK=64, 4 waves (each 64x64 = 4x4 frags).
// MODE 0: out = q_raw bf16; MODE 1: outK/outV = k_raw/v_raw bf16;
// MODE 2: xo f32 = C + hres
// ---------------------------------------------------------------------------
template<int MODE>
__global__ __launch_bounds__(256)
void mm128_kernel(const unsigned short* __restrict__ Abf,
                  const unsigned short* __restrict__ Bbf,
                  const float* __restrict__ hres,
                  unsigned short* __restrict__ outK,
                  unsigned short* __restrict__ outV,
                  float* __restrict__ xo)
{
    __shared__ unsigned short As[128 * 64];
    __shared__ unsigned short Bs[128 * 64];

    const int t  = threadIdx.x;
    const int w  = t >> 6;
    const int l  = t & 63;
    const int lj = l & 15;
    const int lg = l >> 4;
    const int m0 = blockIdx.x * 128;
    const int n0 = blockIdx.y * 128;
    const int wr = w >> 1, wc = w & 1;
    const int rsub = l >> 3;
    const int csw  = ((l & 7) ^ rsub) * 16;

    v4f acc[4][4] = {};

    for (int s = 0; s < 16; ++s) {
        const int k0b = s * 128;
        __syncthreads();
        #pragma unroll
        for (int u = 0; u < 4; ++u) {
            int ra = w * 32 + u * 8;
            gll16((const char*)Abf + (size_t)(m0 + ra + rsub) * 2048 + k0b + csw,
                  (char*)As + ra * 128);
            gll16((const char*)Bbf + (size_t)(n0 + ra + rsub) * 2048 + k0b + csw,
                  (char*)Bs + ra * 128);
        }
        __syncthreads();
        #pragma unroll
        for (int ks = 0; ks < 2; ++ks) {
            bf16x8 af[4], bfr[4];
            #pragma unroll
            for (int m = 0; m < 4; ++m) {
                int row = wr * 64 + m * 16 + lj;
                int c = ks * 4 + lg;
                af[m] = *(const bf16x8*)((const char*)As + row * 128 +
                                         ((c ^ (row & 7)) * 16));
            }
            #pragma unroll
            for (int nn = 0; nn < 4; ++nn) {
                int row = wc * 64 + nn * 16 + lj;
                int c = ks * 4 + lg;
                bfr[nn] = *(const bf16x8*)((const char*)Bs + row * 128 +
                                           ((c ^ (row & 7)) * 16));
            }
            #pragma unroll
            for (int m = 0; m < 4; ++m)
                #pragma unroll
                for (int nn = 0; nn < 4; ++nn)
                    acc[m][nn] = __builtin_amdgcn_mfma_f32_16x16x32_bf16(
                                     af[m], bfr[nn], acc[m][nn], 0, 0, 0);
        }
    }

    #pragma unroll
    for (int m = 0; m < 4; ++m) {
        #pragma unroll
        for (int rr = 0; rr < 4; ++rr) {
            int row = m0 + wr * 64 + m * 16 + 4 * lg + rr;
            #pragma unroll
            for (int nn = 0; nn < 4; ++nn) {
                int col = n0 + wc * 64 + nn * 16 + lj;
                float v = acc[m][nn][rr];
                if constexpr (MODE == 2) {
                    xo[(size_t)row * 1024 + col] = v + hres[(size_t)row * 1024 + col];
                } else if constexpr (MODE == 0) {
                    outK[(size_t)row * 1024 + col] = f2bf(v);
                } else {
                    if (n0 < 1024) outK[(size_t)row * 1024 + col] = f2bf(v);
                    else           outV[(size_t)row * 1024 + (col - 1024)] = f2bf(v);
                }
            }
        }
    }
}

// ---------------------------------------------------------------------------
// DPFP feature kernel — LDS-resident g, fp8 (e4m3) output, chunk-blocked:
//   feat[bh][rb][cell24][row64][16 fp8], stores 1KB contiguous per instr.
// ---------------------------------------------------------------------------
__device__ __forceinline__ float gld(const unsigned short* gr, int idx) {
    return __builtin_bit_cast(float, ((unsigned int)gr[idx]) << 16);
}

template<int FBASE>
__device__ __forceinline__ void dpfp_half8(const unsigned short* __restrict__ gr,
                                           unsigned char* __restrict__ drow)
{
    #pragma unroll
    for (int c = 0; c < 12; ++c) {
        unsigned int w4[4];
        #pragma unroll
        for (int q4 = 0; q4 < 4; ++q4) {
            float p[4];
            #pragma unroll
            for (int e = 0; e < 4; ++e) {
                const int f  = FBASE + c * 16 + q4 * 4 + e;
                const int r  = (f >> 7) + 1;
                const int tt = f & 127;
                const int uu = (tt - r) & 127;
                p[e] = gld(gr, tt) * gld(gr, uu);
            }
            int v = __builtin_amdgcn_cvt_pk_fp8_f32(p[0], p[1], 0, false);
            v     = __builtin_amdgcn_cvt_pk_fp8_f32(p[2], p[3], v, true);
            w4[q4] = (unsigned int)v;
        }
        u32x4 st = {w4[0], w4[1], w4[2], w4[3]};
        *(u32x4*)(drow + c * 1024) = st;
    }
}

__global__ __launch_bounds__(256)
void dpfp_kernel(const unsigned short* __restrict__ qraw,
                 const unsigned short* __restrict__ kraw,
                 unsigned char* __restrict__ qf, unsigned char* __restrict__ kf)
{
    __shared__ unsigned short G[128 * 138];

    const int t   = threadIdx.x;
    const int blk = blockIdx.x;

    const unsigned short* src; unsigned char* dst; int b, hh, seq0;
    if (blk < 512) {
        int bh = blk >> 2, ig = blk & 3;
        b = bh >> 4; hh = bh & 15; seq0 = ig * 128;
        src = qraw; dst = qf + (size_t)bh * 196608;
    } else {
        int blk2 = blk - 512;
        int bh = blk2 >> 3, jg = blk2 & 7;
        b = bh >> 4; hh = bh & 15; seq0 = jg * 128;
        src = kraw; dst = kf + (size_t)bh * 393216;
    }

    #pragma unroll
    for (int p = 0; p < 4; ++p) {
        int u   = p * 256 + t;
        int row = u >> 3;
        int c0  = (u & 7) * 8;
        u32x4 x = *(const u32x4*)(src + ((size_t)(seq0 + row) * 8 + b) * 1024 +
                                  hh * 64 + c0);
        char* gbase = (char*)G + row * 276 + c0 * 2;
        #pragma unroll
        for (int k = 0; k < 4; ++k) {
            unsigned int xk = x[k];
            float x0 = __builtin_bit_cast(float, xk << 16);
            float x1 = __builtin_bit_cast(float, xk & 0xffff0000u);
            float a0 = fmaxf(x0, 0.f), a1 = fmaxf(x1, 0.f);
            float b0 = fmaxf(-x0, 0.f), b1 = fmaxf(-x1, 0.f);
            unsigned int lo, hig;
            asm("v_cvt_pk_bf16_f32 %0, %1, %2" : "=v"(lo) : "v"(a0), "v"(a1));
            asm("v_cvt_pk_bf16_f32 %0, %1, %2" : "=v"(hig) : "v"(b0), "v"(b1));
            *(unsigned int*)(gbase + k * 4)       = lo;
            *(unsigned int*)(gbase + 128 + k * 4) = hig;
        }
    }
    __syncthreads();

    const int w    = t >> 6;
    const int l    = t & 63;
    const int rowc = (w >> 1) * 64 + l;
    const int hs   = w & 1;
    const unsigned short* gr = G + rowc * 138;
    const int seq = seq0 + rowc;
    unsigned char* drow = dst + (size_t)(seq >> 6) * 24576 + (seq & 63) * 16 +
                          hs * 12288;
    if (hs == 0) dpfp_half8<0>(gr, drow);
    else         dpfp_half8<192>(gr, drow);
}

// ---------------------------------------------------------------------------
// V transpose: v_raw [8192=(j,b)][1024=(h,d)] bf16 -> vt [b,h][d][KLEN] bf16.
// ---------------------------------------------------------------------------
__global__ __launch_bounds__(256)
void vtrans_kernel(const unsigned short* __restrict__ vraw,
                   unsigned short* __restrict__ vt)
{
    __shared__ unsigned short S[256][72];
    const int t  = threadIdx.x;
    const int jc = blockIdx.x, hh = blockIdx.y, b = blockIdx.z;
    const unsigned short* src = vraw + (size_t)((jc * 256 + t) * 8 + b) * 1024 + hh * 64;
    #pragma unroll
    for (int c = 0; c < 8; ++c)
        *(u32x4*)&S[t][c * 8] = *(const u32x4*)(src + c * 8);
    __syncthreads();
    const int d = t >> 2, qq = t & 3;
    unsigned short* dst = vt + ((size_t)(b * NH + hh) * HD + d) * KLEN + jc * 256 + qq * 64;
    #pragma unroll
    for (int c8 = 0; c8 < 8; ++c8) {
        u16x8 o;
        #pragma unroll
        for (int e = 0; e < 8; ++e) o[e] = S[qq * 64 + c8 * 8 + e][d];
        *(u16x8*)(dst + c8 * 8) = o;
    }
}

// ---------------------------------------------------------------------------
// MFMA attention v4: fp8 K/Q (32x32x16_fp8_fp8 QK^T), swapped QK^T, in-reg P
// (cvt_pk + permlane32_swap), bf16 PV. K staged LINEAR (identity chunk layout
// is conflict-free for b64 frag reads). KVBLK=64, simple stage->sync->compute
// loop (R8 structure), setprio around MFMA clusters. LDS ~33KB.
// ---------------------------------------------------------------------------
__global__ __launch_bounds__(256, 2)
void attn_mfma_kernel(const unsigned char* __restrict__ qf,
                      const unsigned char* __restrict__ kf,
                      const unsigned short* __restrict__ vt,
                      unsigned short* __restrict__ avec)
{
    __shared__ unsigned char Ks[64 * 384];    // 24KB fp8: [cell24][row64][16B]
    __shared__ unsigned short Vs[64 * 64];    // 8KB bf16: rows(d) 128B, swizzled
    __shared__ float Ds[4][32];

    const int t  = threadIdx.x;
    const int w  = t >> 6;
    const int l  = t & 63;
    const int li = l & 31;
    const int hi = l >> 5;

    const int bid = blockIdx.x;
    const int it  = (bid >> 3) & 3;
    const int P   = ((bid >> 5) << 3) + (bid & 7);
    const int n   = P & 15;
    const int b   = P >> 4;

    const unsigned char* qpan = qf + (size_t)P * 196608;
    const unsigned char* kpan = kf + (size_t)P * 393216;
    const char* vpan = (const char*)(vt + (size_t)P * HD * KLEN);

    int voff[2];
    #pragma unroll
    for (int uu = 0; uu < 2; ++uu) {
        int s  = (w * 2 + uu) * 64 + l;
        int d  = s >> 3;
        int cl = s & 7;
        int cg = cl ^ (d & 7);
        voff[uu] = d * (KLEN * 2) + cg * 16;
    }

    // Q fragments (B operand): lane(col=i=li, k=16ks+8hi+e), fp8 8B each
    long qfr[24];
    {
        const unsigned char* qb = qpan + (size_t)(it * 2 + (w >> 1)) * 24576 +
                                  ((w & 1) * 32 + li) * 16 + hi * 8;
        #pragma unroll
        for (int ks = 0; ks < 24; ++ks)
            qfr[ks] = *(const long*)(qb + ks * 1024);
    }

    f32x16 num[2] = {};
    float den_acc = 0.f;

    const int ig         = it * 128 + w * 32 + li;
    const int my_jt_end  = 2 * it + 8 + (w >> 1);
    const int jt_blk_end = 2 * it + 9;

    for (int jt = 0; jt <= jt_blk_end; ++jt) {
        __syncthreads();
        // ---- stage K (24KB linear!) + V tile ----
        const unsigned char* ktile = kpan + (size_t)jt * 24576;
        #pragma unroll
        for (int u = 0; u < 6; ++u)
            gll16(ktile + (w * 6 + u) * 1024 + l * 16, Ks + (w * 6 + u) * 1024);
        const char* vtile = vpan + jt * 128;
        #pragma unroll
        for (int uu = 0; uu < 2; ++uu)
            gll16(vtile + voff[uu], (char*)Vs + (w * 2 + uu) * 1024);
        __syncthreads();

        if (jt > my_jt_end) continue;

        // ---- S^T = K·Q (fp8): sacc[jh] holds S[j=jh*32+crow][i=li] ----
        f32x16 sacc0 = {};
        f32x16 sacc1 = {};
        __builtin_amdgcn_s_setprio(1);
        #pragma unroll
        for (int ks = 0; ks < 24; ++ks) {
            long k0 = *(const long*)(Ks + ks * 1024 + li * 16 + hi * 8);
            long k1 = *(const long*)(Ks + ks * 1024 + (32 + li) * 16 + hi * 8);
            sacc0 = __builtin_amdgcn_mfma_f32_32x32x16_fp8_fp8(k0, qfr[ks], sacc0, 0, 0, 0);
            sacc1 = __builtin_amdgcn_mfma_f32_32x32x16_fp8_fp8(k1, qfr[ks], sacc1, 0, 0, 0);
        }
        __builtin_amdgcn_s_setprio(0);

        // ---- causal mask on the diagonal tile + den accumulate ----
        if (jt == my_jt_end) {
            const int joff = jt * 64 - MLEN + 4 * hi;
            #pragma unroll
            for (int reg = 0; reg < 16; ++reg) {
                int jr = (reg & 3) + 8 * (reg >> 2);
                if (joff + jr > ig)      sacc0[reg] = 0.f;
                if (joff + 32 + jr > ig) sacc1[reg] = 0.f;
            }
        }
        {
            float dpart = 0.f;
            #pragma unroll
            for (int reg = 0; reg < 16; ++reg) dpart += sacc0[reg] + sacc1[reg];
            den_acc += dpart + __shfl_xor(dpart, 32);
        }

        // ---- P -> bf16 A-frags (cvt_pk + permlane32_swap), PV MFMA ----
        #pragma unroll
        for (int jf = 0; jf < 2; ++jf) {
            const f32x16 sc = jf ? sacc1 : sacc0;
            unsigned int c01, c23, c45, c67, c89, cab, ccd, cef;
            asm("v_cvt_pk_bf16_f32 %0, %1, %2" : "=v"(c01) : "v"(sc[0]),  "v"(sc[1]));
            asm("v_cvt_pk_bf16_f32 %0, %1, %2" : "=v"(c23) : "v"(sc[2]),  "v"(sc[3]));
            asm("v_cvt_pk_bf16_f32 %0, %1, %2" : "=v"(c45) : "v"(sc[4]),  "v"(sc[5]));
            asm("v_cvt_pk_bf16_f32 %0, %1, %2" : "=v"(c67) : "v"(sc[6]),  "v"(sc[7]));
            asm("v_cvt_pk_bf16_f32 %0, %1, %2" : "=v"(c89) : "v"(sc[8]),  "v"(sc[9]));
            asm("v_cvt_pk_bf16_f32 %0, %1, %2" : "=v"(cab) : "v"(sc[10]), "v"(sc[11]));
            asm("v_cvt_pk_bf16_f32 %0, %1, %2" : "=v"(ccd) : "v"(sc[12]), "v"(sc[13]));
            asm("v_cvt_pk_bf16_f32 %0, %1, %2" : "=v"(cef) : "v"(sc[14]), "v"(sc[15]));
            u32x2 r0 = __builtin_amdgcn_permlane32_swap(c01, c45, false, false);
            u32x2 r1 = __builtin_amdgcn_permlane32_swap(c23, c67, false, false);
            u32x2 r2 = __builtin_amdgcn_permlane32_swap(c89, ccd, false, false);
            u32x2 r3 = __builtin_amdgcn_permlane32_swap(cab, cef, false, false);
            u32x4 pw0 = {r0.x, r1.x, r0.y, r1.y};
            u32x4 pw1 = {r2.x, r3.x, r2.y, r3.y};
            bf16x8 pa0 = __builtin_bit_cast(bf16x8, pw0);
            bf16x8 pa1 = __builtin_bit_cast(bf16x8, pw1);
            __builtin_amdgcn_s_setprio(1);
            #pragma unroll
            for (int dd = 0; dd < 2; ++dd) {
                int d = dd * 32 + li;
                {
                    int cs = (jf * 4 + hi) ^ (d & 7);
                    bf16x8 vb = *(const bf16x8*)((const char*)Vs + d * 128 + cs * 16);
                    num[dd] = __builtin_amdgcn_mfma_f32_32x32x16_bf16(pa0, vb, num[dd], 0, 0, 0);
                }
                {
                    int cs = (jf * 4 + 2 + hi) ^ (d & 7);
                    bf16x8 vb = *(const bf16x8*)((const char*)Vs + d * 128 + cs * 16);
                    num[dd] = __builtin_amdgcn_mfma_f32_32x32x16_bf16(pa1, vb, num[dd], 0, 0, 0);
                }
            }
            __builtin_amdgcn_s_setprio(0);
        }
    }

    // ---- den broadcast via tiny per-wave LDS, normalize, store bf16 ----
    if (l < 32) Ds[w][l] = den_acc;
    #pragma unroll
    for (int reg = 0; reg < 16; ++reg) {
        int i_loc = (reg & 3) + 8 * (reg >> 2) + 4 * hi;
        float dv = Ds[w][i_loc];
        float minv = ATT_SCALE / (dv * ATT_SCALE + EPSV);
        int ig2 = it * 128 + w * 32 + i_loc;
        unsigned short* orow = avec + ((size_t)ig2 * BB + b) * DMODEL + n * HD;
        orow[li]      = f2bf(num[0][reg] * minv);
        orow[32 + li] = f2bf(num[1][reg] * minv);
    }
}

// ---------------------------------------------------------------------------
// Row LayerNorm over DM=1024.
// ---------------------------------------------------------------------------
__global__ __launch_bounds__(256)
void ln_kernel(const float* __restrict__ x, const float* __restrict__ gamma,
               const float* __restrict__ beta, float* __restrict__ out)
{
    const int row = blockIdx.x;
    const int t = threadIdx.x;
    const float* xr = x + (size_t)row * DMODEL;
    v4f xv = *(const v4f*)(xr + (t << 2));
    float s1 = xv[0] + xv[1] + xv[2] + xv[3];
    float s2 = xv[0]*xv[0] + xv[1]*xv[1] + xv[2]*xv[2] + xv[3]*xv[3];
    #pragma unroll
    for (int off = 32; off > 0; off >>= 1) {
        s1 += __shfl_down(s1, off);
        s2 += __shfl_down(s2, off);
    }
    __shared__ float red[2][4];
    __shared__ float mv[2];
    const int wave = t >> 6;
    if ((t & 63) == 0) { red[0][wave] = s1; red[1][wave] = s2; }
    __syncthreads();
    if (t == 0) {
        float a = red[0][0] + red[0][1] + red[0][2] + red[0][3];
        float q = red[1][0] + red[1][1] + red[1][2] + red[1][3];
        float mu  = a * (1.f / DMODEL);
        float var = q * (1.f / DMODEL) - mu * mu;
        mv[0] = mu;
        mv[1] = rsqrtf(var + EPSV);
    }
    __syncthreads();
    float mu = mv[0], rs = mv[1];
    v4f gv = *(const v4f*)(gamma + (t << 2));
    v4f bv = *(const v4f*)(beta + (t << 2));
    v4f o;
    #pragma unroll
    for (int e = 0; e < 4; ++e) o[e] = (xv[e] - mu) * rs * gv[e] + bv[e];
    *(v4f*)(out + (size_t)row * DMODEL + (t << 2)) = o;
}

extern "C" void kernel_launch(void* const* d_in, const int* in_sizes, int n_in,
                              void* d_out, int out_size, void* d_ws, size_t ws_size,
                              hipStream_t stream)
{
    const float* h     = (const float*)d_in[0];
    const float* mems  = (const float*)d_in[1];
    const float* Wq    = (const float*)d_in[2];
    const float* Wkv   = (const float*)d_in[3];
    const float* Wo    = (const float*)d_in[4];
    const float* gamma = (const float*)d_in[5];
    const float* beta  = (const float*)d_in[6];
    // d_in[7] = attn_mask: causal structure computed analytically, ignored.

    char* ws = (char*)d_ws;
    unsigned char* qf    = (unsigned char*)(ws);              // [0, 25.17M) fp8
    unsigned char* kf    = (unsigned char*)(ws + 25165824);   // [25.17M, 75.50M) fp8
    unsigned short* kraw = (unsigned short*)(ws + 150994944); // 16.78M bf16
    unsigned short* vt   = kraw;                              // overlay after dpfp
    unsigned short* vraw = (unsigned short*)(ws + 167772160); // 16.78M
    unsigned short* cbf  = (unsigned short*)(ws + 184549376); // 16.78M
    unsigned short* qraw = cbf;                               // overlay mems-half after mm1
    unsigned short* avec = cbf;                               // overlay after dpfp
    float* xws = (float*)(ws);                                // overlay qf after attn

    unsigned short* wqb  = (unsigned short*)d_out;            // bf16 weights in d_out
    unsigned short* wkvb = wqb + 1048576;
    unsigned short* wob  = wkvb + 2097152;

    cvt_all_kernel<<<12288, 256, 0, stream>>>(h, mems, Wq, Wkv, Wo, cbf, wqb, wkvb, wob);
    mm128_kernel<1><<<dim3(64, 16), 256, 0, stream>>>(cbf, wkvb, nullptr, kraw, vraw, nullptr);
    mm128_kernel<0><<<dim3(32, 8), 256, 0, stream>>>(cbf + 4194304, wqb, nullptr, qraw, nullptr, nullptr);
    dpfp_kernel<<<1536, 256, 0, stream>>>(qraw, kraw, qf, kf);
    vtrans_kernel<<<dim3(4, 16, 8), 256, 0, stream>>>(vraw, vt);
    attn_mfma_kernel<<<512, 256, 0, stream>>>(qf, kf, vt, avec);
    mm128_kernel<2><<<dim3(32, 8), 256, 0, stream>>>(avec, wob, h, nullptr, nullptr, xws);
    ln_kernel<<<4096, 256, 0, stream>>>(xws, gamma, beta, (float*)d_out);
}

// Round 11
// 184.101 us; speedup vs baseline: 1.2163x; 1.0351x over previous
//
#include <hip/hip_runtime.h>

#define QLEN 512
#define MLEN 512
#define KLEN 1024
#define BB   8
#define DMODEL 1024
#define NH   16
#define HD   64
#define NF   384
#define ATT_SCALE 0.125f
#define EPSV 1e-5f

typedef float v4f __attribute__((ext_vector_type(4)));
typedef float f32x16 __attribute__((ext_vector_type(16)));
typedef short bf16x8 __attribute__((ext_vector_type(8)));
typedef unsigned int u32x4 __attribute__((ext_vector_type(4)));
typedef unsigned int u32x2 __attribute__((ext_vector_type(2)));
typedef unsigned short u16x8 __attribute__((ext_vector_type(8)));

__device__ __forceinline__ unsigned short f2bf(float f) {
    unsigned int x = __builtin_bit_cast(unsigned int, f);
    x += 0x7fffu + ((x >> 16) & 1u);
    return (unsigned short)(x >> 16);
}

__device__ __forceinline__ void gll16(const void* g, void* l) {
    __builtin_amdgcn_global_load_lds(
        (const __attribute__((address_space(1))) unsigned int*)g,
        (__attribute__((address_space(3))) unsigned int*)l, 16, 0, 0);
}

// fp8 feature layout (bytes): feat[bh][rb][cell:24][row:64][16 fp8]

// ---------------------------------------------------------------------------
// Fused f32->bf16 converts: mems+h -> cbf (c matrix), weights -> bf16 scratch
// ---------------------------------------------------------------------------
__global__ __launch_bounds__(256)
void cvt_all_kernel(const float* __restrict__ h, const float* __restrict__ mems,
                    const float* __restrict__ Wq, const float* __restrict__ Wkv,
                    const float* __restrict__ Wo,
                    unsigned short* __restrict__ cbf, unsigned short* __restrict__ wqb,
                    unsigned short* __restrict__ wkvb, unsigned short* __restrict__ wob)
{
    int blk = blockIdx.x;
    const float* src; unsigned short* dst; int base;
    if (blk < 4096)       { src = mems; dst = cbf;           base = blk; }
    else if (blk < 8192)  { src = h;    dst = cbf + 4194304; base = blk - 4096; }
    else if (blk < 9216)  { src = Wq;   dst = wqb;           base = blk - 8192; }
    else if (blk < 11264) { src = Wkv;  dst = wkvb;          base = blk - 9216; }
    else                  { src = Wo;   dst = wob;           base = blk - 11264; }
    int i = (base * 256 + threadIdx.x) * 4;
    v4f v = *(const v4f*)(src + i);
    unsigned int p0, p1;
    asm("v_cvt_pk_bf16_f32 %0, %1, %2" : "=v"(p0) : "v"(v[0]), "v"(v[1]));
    asm("v_cvt_pk_bf16_f32 %0, %1, %2" : "=v"(p1) : "v"(v[2]), "v"(v[3]));
    uint2 u; u.x = p0; u.y = p1;
    *(uint2*)(dst + i) = u;
}

// ---------------------------------------------------------------------------
// 256^2-tile MFMA GEMM for kv-proj: BK=64, 512 threads (8 waves, wave tile
// 128x64 = 8x4 16x16x32 frags -> 24 ds_read : 64 MFMA per K-step, MFMA-bound).
// Double-buffered 128KB LDS; STAGE(t+1) issued before compute(t) so the 8
// global_load_lds fly under the MFMA phase; one vmcnt(0)+barrier per step.
// Output: cols <1024 -> outK bf16, else outV bf16.
// ---------------------------------------------------------------------------
__global__ __launch_bounds__(512)
void gemm256_kernel(const unsigned short* __restrict__ Abf,
                    const unsigned short* __restrict__ Bbf,
                    unsigned short* __restrict__ outK,
                    unsigned short* __restrict__ outV)
{
    __shared__ unsigned short As[2][256 * 64];   // 32KB each
    __shared__ unsigned short Bs[2][256 * 64];   // 32KB each

    const int t  = threadIdx.x;
    const int w  = t >> 6;          // 0..7
    const int l  = t & 63;
    const int lj = l & 15;
    const int lg = l >> 4;
    const int m0 = blockIdx.x * 256;
    const int n0 = blockIdx.y * 256;
    const int wr = w >> 2;          // 0..1: row half (128 rows)
    const int wc = w & 3;           // 0..3: col quarter (64 cols)
    const int rsub = l >> 3;
    const int csw  = ((l & 7) ^ rsub) * 16;

    v4f acc[8][4] = {};

    for (int s = 0; s < 16; ++s) {
        const int cur = s & 1;
        if (s == 0) {
            // prologue stage of tile 0 into buf 0
            #pragma unroll
            for (int u = 0; u < 4; ++u) {
                int inst = w * 4 + u;
                gll16((const char*)Abf + (size_t)(m0 + inst * 8 + rsub) * 2048 + csw,
                      (char*)As[0] + inst * 1024);
                gll16((const char*)Bbf + (size_t)(n0 + inst * 8 + rsub) * 2048 + csw,
                      (char*)Bs[0] + inst * 1024);
            }
            asm volatile("s_waitcnt vmcnt(0)" ::: "memory");
            __builtin_amdgcn_s_barrier();
        }
        // ---- issue stage for tile s+1 into the other buffer ----
        if (s < 15) {
            const int k0b = (s + 1) * 128;
            #pragma unroll
            for (int u = 0; u < 4; ++u) {
                int inst = w * 4 + u;
                gll16((const char*)Abf + (size_t)(m0 + inst * 8 + rsub) * 2048 + k0b + csw,
                      (char*)As[cur ^ 1] + inst * 1024);
                gll16((const char*)Bbf + (size_t)(n0 + inst * 8 + rsub) * 2048 + k0b + csw,
                      (char*)Bs[cur ^ 1] + inst * 1024);
            }
        }
        // ---- compute on buf[cur] ----
        __builtin_amdgcn_s_setprio(1);
        #pragma unroll
        for (int ks = 0; ks < 2; ++ks) {
            bf16x8 af[8], bfr[4];
            #pragma unroll
            for (int m = 0; m < 8; ++m) {
                int row = wr * 128 + m * 16 + lj;
                int c = ks * 4 + lg;
                af[m] = *(const bf16x8*)((const char*)As[cur] + row * 128 +
                                         ((c ^ (row & 7)) * 16));
            }
            #pragma unroll
            for (int nn = 0; nn < 4; ++nn) {
                int row = wc * 64 + nn * 16 + lj;
                int c = ks * 4 + lg;
                bfr[nn] = *(const bf16x8*)((const char*)Bs[cur] + row * 128 +
                                           ((c ^ (row & 7)) * 16));
            }
            #pragma unroll
            for (int m = 0; m < 8; ++m)
                #pragma unroll
                for (int nn = 0; nn < 4; ++nn)
                    acc[m][nn] = __builtin_amdgcn_mfma_f32_16x16x32_bf16(
                                     af[m], bfr[nn], acc[m][nn], 0, 0, 0);
        }
        __builtin_amdgcn_s_setprio(0);
        if (s < 15) {
            // staged loads have flown under the compute; drain + sync
            asm volatile("s_waitcnt vmcnt(0)" ::: "memory");
            __builtin_amdgcn_s_barrier();
        }
    }

    // ---- epilogue: bf16 stores, k/v split at col 1024 (256-aligned blocks
    // never straddle the boundary) ----
    #pragma unroll
    for (int m = 0; m < 8; ++m) {
        #pragma unroll
        for (int rr = 0; rr < 4; ++rr) {
            int row = m0 + wr * 128 + m * 16 + 4 * lg + rr;
            #pragma unroll
            for (int nn = 0; nn < 4; ++nn) {
                int col = n0 + wc * 64 + nn * 16 + lj;
                float v = acc[m][nn][rr];
                if (n0 < 1024) outK[(size_t)row * 1024 + col] = f2bf(v);
                else           outV[(size_t)row * 1024 + (col - 1024)] = f2bf(v);
            }
        }
    }
}

// ---------------------------------------------------------------------------
// Pure MFMA GEMM, 128x128 tile, BK=64, 4 waves (each 64x64 = 4x4 frags).
// MODE 0: out = q_raw bf16; MODE 2: xo f32 = C + hres
// ---------------------------------------------------------------------------
template<int MODE>
__global__ __launch_bounds__(256)
void mm128_kernel(const unsigned short* __restrict__ Abf,
                  const unsigned short* __restrict__ Bbf,
                  const float* __restrict__ hres,
                  unsigned short* __restrict__ outK,
                  float* __restrict__ xo)
{
    __shared__ unsigned short As[128 * 64];
    __shared__ unsigned short Bs[128 * 64];

    const int t  = threadIdx.x;
    const int w  = t >> 6;
    const int l  = t & 63;
    const int lj = l & 15;
    const int lg = l >> 4;
    const int m0 = blockIdx.x * 128;
    const int n0 = blockIdx.y * 128;
    const int wr = w >> 1, wc = w & 1;
    const int rsub = l >> 3;
    const int csw  = ((l & 7) ^ rsub) * 16;

    v4f acc[4][4] = {};

    for (int s = 0; s < 16; ++s) {
        const int k0b = s * 128;
        __syncthreads();
        #pragma unroll
        for (int u = 0; u < 4; ++u) {
            int ra = w * 32 + u * 8;
            gll16((const char*)Abf + (size_t)(m0 + ra + rsub) * 2048 + k0b + csw,
                  (char*)As + ra * 128);
            gll16((const char*)Bbf + (size_t)(n0 + ra + rsub) * 2048 + k0b + csw,
                  (char*)Bs + ra * 128);
        }
        __syncthreads();
        #pragma unroll
        for (int ks = 0; ks < 2; ++ks) {
            bf16x8 af[4], bfr[4];
            #pragma unroll
            for (int m = 0; m < 4; ++m) {
                int row = wr * 64 + m * 16 + lj;
                int c = ks * 4 + lg;
                af[m] = *(const bf16x8*)((const char*)As + row * 128 +
                                         ((c ^ (row & 7)) * 16));
            }
            #pragma unroll
            for (int nn = 0; nn < 4; ++nn) {
                int row = wc * 64 + nn * 16 + lj;
                int c = ks * 4 + lg;
                bfr[nn] = *(const bf16x8*)((const char*)Bs + row * 128 +
                                           ((c ^ (row & 7)) * 16));
            }
            #pragma unroll
            for (int m = 0; m < 4; ++m)
                #pragma unroll
                for (int nn = 0; nn < 4; ++nn)
                    acc[m][nn] = __builtin_amdgcn_mfma_f32_16x16x32_bf16(
                                     af[m], bfr[nn], acc[m][nn], 0, 0, 0);
        }
    }

    #pragma unroll
    for (int m = 0; m < 4; ++m) {
        #pragma unroll
        for (int rr = 0; rr < 4; ++rr) {
            int row = m0 + wr * 64 + m * 16 + 4 * lg + rr;
            #pragma unroll
            for (int nn = 0; nn < 4; ++nn) {
                int col = n0 + wc * 64 + nn * 16 + lj;
                float v = acc[m][nn][rr];
                if constexpr (MODE == 2) {
                    xo[(size_t)row * 1024 + col] = v + hres[(size_t)row * 1024 + col];
                } else {
                    outK[(size_t)row * 1024 + col] = f2bf(v);
                }
            }
        }
    }
}

// ---------------------------------------------------------------------------
// DPFP feature kernel — LDS-resident g, fp8 (e4m3) output, chunk-blocked:
//   feat[bh][rb][cell24][row64][16 fp8], stores 1KB contiguous per instr.
// ---------------------------------------------------------------------------
__device__ __forceinline__ float gld(const unsigned short* gr, int idx) {
    return __builtin_bit_cast(float, ((unsigned int)gr[idx]) << 16);
}

template<int FBASE>
__device__ __forceinline__ void dpfp_half8(const unsigned short* __restrict__ gr,
                                           unsigned char* __restrict__ drow)
{
    #pragma unroll
    for (int c = 0; c < 12; ++c) {
        unsigned int w4[4];
        #pragma unroll
        for (int q4 = 0; q4 < 4; ++q4) {
            float p[4];
            #pragma unroll
            for (int e = 0; e < 4; ++e) {
                const int f  = FBASE + c * 16 + q4 * 4 + e;
                const int r  = (f >> 7) + 1;
                const int tt = f & 127;
                const int uu = (tt - r) & 127;
                p[e] = gld(gr, tt) * gld(gr, uu);
            }
            int v = __builtin_amdgcn_cvt_pk_fp8_f32(p[0], p[1], 0, false);
            v     = __builtin_amdgcn_cvt_pk_fp8_f32(p[2], p[3], v, true);
            w4[q4] = (unsigned int)v;
        }
        u32x4 st = {w4[0], w4[1], w4[2], w4[3]};
        *(u32x4*)(drow + c * 1024) = st;
    }
}

__global__ __launch_bounds__(256)
void dpfp_kernel(const unsigned short* __restrict__ qraw,
                 const unsigned short* __restrict__ kraw,
                 unsigned char* __restrict__ qf, unsigned char* __restrict__ kf)
{
    __shared__ unsigned short G[128 * 138];

    const int t   = threadIdx.x;
    const int blk = blockIdx.x;

    const unsigned short* src; unsigned char* dst; int b, hh, seq0;
    if (blk < 512) {
        int bh = blk >> 2, ig = blk & 3;
        b = bh >> 4; hh = bh & 15; seq0 = ig * 128;
        src = qraw; dst = qf + (size_t)bh * 196608;
    } else {
        int blk2 = blk - 512;
        int bh = blk2 >> 3, jg = blk2 & 7;
        b = bh >> 4; hh = bh & 15; seq0 = jg * 128;
        src = kraw; dst = kf + (size_t)bh * 393216;
    }

    #pragma unroll
    for (int p = 0; p < 4; ++p) {
        int u   = p * 256 + t;
        int row = u >> 3;
        int c0  = (u & 7) * 8;
        u32x4 x = *(const u32x4*)(src + ((size_t)(seq0 + row) * 8 + b) * 1024 +
                                  hh * 64 + c0);
        char* gbase = (char*)G + row * 276 + c0 * 2;
        #pragma unroll
        for (int k = 0; k < 4; ++k) {
            unsigned int xk = x[k];
            float x0 = __builtin_bit_cast(float, xk << 16);
            float x1 = __builtin_bit_cast(float, xk & 0xffff0000u);
            float a0 = fmaxf(x0, 0.f), a1 = fmaxf(x1, 0.f);
            float b0 = fmaxf(-x0, 0.f), b1 = fmaxf(-x1, 0.f);
            unsigned int lo, hig;
            asm("v_cvt_pk_bf16_f32 %0, %1, %2" : "=v"(lo) : "v"(a0), "v"(a1));
            asm("v_cvt_pk_bf16_f32 %0, %1, %2" : "=v"(hig) : "v"(b0), "v"(b1));
            *(unsigned int*)(gbase + k * 4)       = lo;
            *(unsigned int*)(gbase + 128 + k * 4) = hig;
        }
    }
    __syncthreads();

    const int w    = t >> 6;
    const int l    = t & 63;
    const int rowc = (w >> 1) * 64 + l;
    const int hs   = w & 1;
    const unsigned short* gr = G + rowc * 138;
    const int seq = seq0 + rowc;
    unsigned char* drow = dst + (size_t)(seq >> 6) * 24576 + (seq & 63) * 16 +
                          hs * 12288;
    if (hs == 0) dpfp_half8<0>(gr, drow);
    else         dpfp_half8<192>(gr, drow);
}

// ---------------------------------------------------------------------------
// V transpose: v_raw [8192=(j,b)][1024=(h,d)] bf16 -> vt [b,h][d][KLEN] bf16.
// ---------------------------------------------------------------------------
__global__ __launch_bounds__(256)
void vtrans_kernel(const unsigned short* __restrict__ vraw,
                   unsigned short* __restrict__ vt)
{
    __shared__ unsigned short S[256][72];
    const int t  = threadIdx.x;
    const int jc = blockIdx.x, hh = blockIdx.y, b = blockIdx.z;
    const unsigned short* src = vraw + (size_t)((jc * 256 + t) * 8 + b) * 1024 + hh * 64;
    #pragma unroll
    for (int c = 0; c < 8; ++c)
        *(u32x4*)&S[t][c * 8] = *(const u32x4*)(src + c * 8);
    __syncthreads();
    const int d = t >> 2, qq = t & 3;
    unsigned short* dst = vt + ((size_t)(b * NH + hh) * HD + d) * KLEN + jc * 256 + qq * 64;
    #pragma unroll
    for (int c8 = 0; c8 < 8; ++c8) {
        u16x8 o;
        #pragma unroll
        for (int e = 0; e < 8; ++e) o[e] = S[qq * 64 + c8 * 8 + e][d];
        *(u16x8*)(dst + c8 * 8) = o;
    }
}

// ---------------------------------------------------------------------------
// MFMA attention v4: fp8 K/Q (32x32x16_fp8_fp8 QK^T), swapped QK^T, in-reg P
// (cvt_pk + permlane32_swap), bf16 PV. K staged LINEAR. KVBLK=64, setprio
// around MFMA clusters. LDS ~33KB.
// ---------------------------------------------------------------------------
__global__ __launch_bounds__(256, 2)
void attn_mfma_kernel(const unsigned char* __restrict__ qf,
                      const unsigned char* __restrict__ kf,
                      const unsigned short* __restrict__ vt,
                      unsigned short* __restrict__ avec)
{
    __shared__ unsigned char Ks[64 * 384];    // 24KB fp8: [cell24][row64][16B]
    __shared__ unsigned short Vs[64 * 64];    // 8KB bf16: rows(d) 128B, swizzled
    __shared__ float Ds[4][32];

    const int t  = threadIdx.x;
    const int w  = t >> 6;
    const int l  = t & 63;
    const int li = l & 31;
    const int hi = l >> 5;

    const int bid = blockIdx.x;
    const int it  = (bid >> 3) & 3;
    const int P   = ((bid >> 5) << 3) + (bid & 7);
    const int n   = P & 15;
    const int b   = P >> 4;

    const unsigned char* qpan = qf + (size_t)P * 196608;
    const unsigned char* kpan = kf + (size_t)P * 393216;
    const char* vpan = (const char*)(vt + (size_t)P * HD * KLEN);

    int voff[2];
    #pragma unroll
    for (int uu = 0; uu < 2; ++uu) {
        int s  = (w * 2 + uu) * 64 + l;
        int d  = s >> 3;
        int cl = s & 7;
        int cg = cl ^ (d & 7);
        voff[uu] = d * (KLEN * 2) + cg * 16;
    }

    // Q fragments (B operand): lane(col=i=li, k=16ks+8hi+e), fp8 8B each
    long qfr[24];
    {
        const unsigned char* qb = qpan + (size_t)(it * 2 + (w >> 1)) * 24576 +
                                  ((w & 1) * 32 + li) * 16 + hi * 8;
        #pragma unroll
        for (int ks = 0; ks < 24; ++ks)
            qfr[ks] = *(const long*)(qb + ks * 1024);
    }

    f32x16 num[2] = {};
    float den_acc = 0.f;

    const int ig         = it * 128 + w * 32 + li;
    const int my_jt_end  = 2 * it + 8 + (w >> 1);
    const int jt_blk_end = 2 * it + 9;

    for (int jt = 0; jt <= jt_blk_end; ++jt) {
        __syncthreads();
        // ---- stage K (24KB linear!) + V tile ----
        const unsigned char* ktile = kpan + (size_t)jt * 24576;
        #pragma unroll
        for (int u = 0; u < 6; ++u)
            gll16(ktile + (w * 6 + u) * 1024 + l * 16, Ks + (w * 6 + u) * 1024);
        const char* vtile = vpan + jt * 128;
        #pragma unroll
        for (int uu = 0; uu < 2; ++uu)
            gll16(vtile + voff[uu], (char*)Vs + (w * 2 + uu) * 1024);
        __syncthreads();

        if (jt > my_jt_end) continue;

        // ---- S^T = K·Q (fp8): sacc[jh] holds S[j=jh*32+crow][i=li] ----
        f32x16 sacc0 = {};
        f32x16 sacc1 = {};
        __builtin_amdgcn_s_setprio(1);
        #pragma unroll
        for (int ks = 0; ks < 24; ++ks) {
            long k0 = *(const long*)(Ks + ks * 1024 + li * 16 + hi * 8);
            long k1 = *(const long*)(Ks + ks * 1024 + (32 + li) * 16 + hi * 8);
            sacc0 = __builtin_amdgcn_mfma_f32_32x32x16_fp8_fp8(k0, qfr[ks], sacc0, 0, 0, 0);
            sacc1 = __builtin_amdgcn_mfma_f32_32x32x16_fp8_fp8(k1, qfr[ks], sacc1, 0, 0, 0);
        }
        __builtin_amdgcn_s_setprio(0);

        // ---- causal mask on the diagonal tile + den accumulate ----
        if (jt == my_jt_end) {
            const int joff = jt * 64 - MLEN + 4 * hi;
            #pragma unroll
            for (int reg = 0; reg < 16; ++reg) {
                int jr = (reg & 3) + 8 * (reg >> 2);
                if (joff + jr > ig)      sacc0[reg] = 0.f;
                if (joff + 32 + jr > ig) sacc1[reg] = 0.f;
            }
        }
        {
            float dpart = 0.f;
            #pragma unroll
            for (int reg = 0; reg < 16; ++reg) dpart += sacc0[reg] + sacc1[reg];
            den_acc += dpart + __shfl_xor(dpart, 32);
        }

        // ---- P -> bf16 A-frags (cvt_pk + permlane32_swap), PV MFMA ----
        #pragma unroll
        for (int jf = 0; jf < 2; ++jf) {
            const f32x16 sc = jf ? sacc1 : sacc0;
            unsigned int c01, c23, c45, c67, c89, cab, ccd, cef;
            asm("v_cvt_pk_bf16_f32 %0, %1, %2" : "=v"(c01) : "v"(sc[0]),  "v"(sc[1]));
            asm("v_cvt_pk_bf16_f32 %0, %1, %2" : "=v"(c23) : "v"(sc[2]),  "v"(sc[3]));
            asm("v_cvt_pk_bf16_f32 %0, %1, %2" : "=v"(c45) : "v"(sc[4]),  "v"(sc[5]));
            asm("v_cvt_pk_bf16_f32 %0, %1, %2" : "=v"(c67) : "v"(sc[6]),  "v"(sc[7]));
            asm("v_cvt_pk_bf16_f32 %0, %1, %2" : "=v"(c89) : "v"(sc[8]),  "v"(sc[9]));
            asm("v_cvt_pk_bf16_f32 %0, %1, %2" : "=v"(cab) : "v"(sc[10]), "v"(sc[11]));
            asm("v_cvt_pk_bf16_f32 %0, %1, %2" : "=v"(ccd) : "v"(sc[12]), "v"(sc[13]));
            asm("v_cvt_pk_bf16_f32 %0, %1, %2" : "=v"(cef) : "v"(sc[14]), "v"(sc[15]));
            u32x2 r0 = __builtin_amdgcn_permlane32_swap(c01, c45, false, false);
            u32x2 r1 = __builtin_amdgcn_permlane32_swap(c23, c67, false, false);
            u32x2 r2 = __builtin_amdgcn_permlane32_swap(c89, ccd, false, false);
            u32x2 r3 = __builtin_amdgcn_permlane32_swap(cab, cef, false, false);
            u32x4 pw0 = {r0.x, r1.x, r0.y, r1.y};
            u32x4 pw1 = {r2.x, r3.x, r2.y, r3.y};
            bf16x8 pa0 = __builtin_bit_cast(bf16x8, pw0);
            bf16x8 pa1 = __builtin_bit_cast(bf16x8, pw1);
            __builtin_amdgcn_s_setprio(1);
            #pragma unroll
            for (int dd = 0; dd < 2; ++dd) {
                int d = dd * 32 + li;
                {
                    int cs = (jf * 4 + hi) ^ (d & 7);
                    bf16x8 vb = *(const bf16x8*)((const char*)Vs + d * 128 + cs * 16);
                    num[dd] = __builtin_amdgcn_mfma_f32_32x32x16_bf16(pa0, vb, num[dd], 0, 0, 0);
                }
                {
                    int cs = (jf * 4 + 2 + hi) ^ (d & 7);
                    bf16x8 vb = *(const bf16x8*)((const char*)Vs + d * 128 + cs * 16);
                    num[dd] = __builtin_amdgcn_mfma_f32_32x32x16_bf16(pa1, vb, num[dd], 0, 0, 0);
                }
            }
            __builtin_amdgcn_s_setprio(0);
        }
    }

    // ---- den broadcast via tiny per-wave LDS, normalize, store bf16 ----
    if (l < 32) Ds[w][l] = den_acc;
    #pragma unroll
    for (int reg = 0; reg < 16; ++reg) {
        int i_loc = (reg & 3) + 8 * (reg >> 2) + 4 * hi;
        float dv = Ds[w][i_loc];
        float minv = ATT_SCALE / (dv * ATT_SCALE + EPSV);
        int ig2 = it * 128 + w * 32 + i_loc;
        unsigned short* orow = avec + ((size_t)ig2 * BB + b) * DMODEL + n * HD;
        orow[li]      = f2bf(num[0][reg] * minv);
        orow[32 + li] = f2bf(num[1][reg] * minv);
    }
}

// ---------------------------------------------------------------------------
// Row LayerNorm over DM=1024.
// ---------------------------------------------------------------------------
__global__ __launch_bounds__(256)
void ln_kernel(const float* __restrict__ x, const float* __restrict__ gamma,
               const float* __restrict__ beta, float* __restrict__ out)
{
    const int row = blockIdx.x;
    const int t = threadIdx.x;
    const float* xr = x + (size_t)row * DMODEL;
    v4f xv = *(const v4f*)(xr + (t << 2));
    float s1 = xv[0] + xv[1] + xv[2] + xv[3];
    float s2 = xv[0]*xv[0] + xv[1]*xv[1] + xv[2]*xv[2] + xv[3]*xv[3];
    #pragma unroll
    for (int off = 32; off > 0; off >>= 1) {
        s1 += __shfl_down(s1, off);
        s2 += __shfl_down(s2, off);
    }
    __shared__ float red[2][4];
    __shared__ float mv[2];
    const int wave = t >> 6;
    if ((t & 63) == 0) { red[0][wave] = s1; red[1][wave] = s2; }
    __syncthreads();
    if (t == 0) {
        float a = red[0][0] + red[0][1] + red[0][2] + red[0][3];
        float q = red[1][0] + red[1][1] + red[1][2] + red[1][3];
        float mu  = a * (1.f / DMODEL);
        float var = q * (1.f / DMODEL) - mu * mu;
        mv[0] = mu;
        mv[1] = rsqrtf(var + EPSV);
    }
    __syncthreads();
    float mu = mv[0], rs = mv[1];
    v4f gv = *(const v4f*)(gamma + (t << 2));
    v4f bv = *(const v4f*)(beta + (t << 2));
    v4f o;
    #pragma unroll
    for (int e = 0; e < 4; ++e) o[e] = (xv[e] - mu) * rs * gv[e] + bv[e];
    *(v4f*)(out + (size_t)row * DMODEL + (t << 2)) = o;
}

extern "C" void kernel_launch(void* const* d_in, const int* in_sizes, int n_in,
                              void* d_out, int out_size, void* d_ws, size_t ws_size,
                              hipStream_t stream)
{
    const float* h     = (const float*)d_in[0];
    const float* mems  = (const float*)d_in[1];
    const float* Wq    = (const float*)d_in[2];
    const float* Wkv   = (const float*)d_in[3];
    const float* Wo    = (const float*)d_in[4];
    const float* gamma = (const float*)d_in[5];
    const float* beta  = (const float*)d_in[6];
    // d_in[7] = attn_mask: causal structure computed analytically, ignored.

    char* ws = (char*)d_ws;
    unsigned char* qf    = (unsigned char*)(ws);              // [0, 25.17M) fp8
    unsigned char* kf    = (unsigned char*)(ws + 25165824);   // [25.17M, 75.50M) fp8
    unsigned short* kraw = (unsigned short*)(ws + 150994944); // 16.78M bf16
    unsigned short* vt   = kraw;                              // overlay after dpfp
    unsigned short* vraw = (unsigned short*)(ws + 167772160); // 16.78M
    unsigned short* cbf  = (unsigned short*)(ws + 184549376); // 16.78M
    unsigned short* qraw = cbf;                               // overlay mems-half after mm1
    unsigned short* avec = cbf;                               // overlay after dpfp
    float* xws = (float*)(ws);                                // overlay qf after attn

    unsigned short* wqb  = (unsigned short*)d_out;            // bf16 weights in d_out
    unsigned short* wkvb = wqb + 1048576;
    unsigned short* wob  = wkvb + 2097152;

    cvt_all_kernel<<<12288, 256, 0, stream>>>(h, mems, Wq, Wkv, Wo, cbf, wqb, wkvb, wob);
    gemm256_kernel<<<dim3(32, 8), 512, 0, stream>>>(cbf, wkvb, kraw, vraw);
    mm128_kernel<0><<<dim3(32, 8), 256, 0, stream>>>(cbf + 4194304, wqb, nullptr, qraw, nullptr);
    dpfp_kernel<<<1536, 256, 0, stream>>>(qraw, kraw, qf, kf);
    vtrans_kernel<<<dim3(4, 16, 8), 256, 0, stream>>>(vraw, vt);
    attn_mfma_kernel<<<512, 256, 0, stream>>>(qf, kf, vt, avec);
    mm128_kernel<2><<<dim3(32, 8), 256, 0, stream>>>(avec, wob, h, nullptr, xws);
    ln_kernel<<<4096, 256, 0, stream>>>(xws, gamma, beta, (float*)d_out);
}

// Round 12
// 182.527 us; speedup vs baseline: 1.2268x; 1.0086x over previous
//
#include <hip/hip_runtime.h>

#define QLEN 512
#define MLEN 512
#define KLEN 1024
#define BB   8
#define DMODEL 1024
#define NH   16
#define HD   64
#define NF   384
#define ATT_SCALE 0.125f
#define EPSV 1e-5f

typedef float v4f __attribute__((ext_vector_type(4)));
typedef float f32x16 __attribute__((ext_vector_type(16)));
typedef short bf16x8 __attribute__((ext_vector_type(8)));
typedef long lx2 __attribute__((ext_vector_type(2)));
typedef unsigned int u32x4 __attribute__((ext_vector_type(4)));
typedef unsigned int u32x2 __attribute__((ext_vector_type(2)));
typedef unsigned short u16x8 __attribute__((ext_vector_type(8)));

__device__ __forceinline__ unsigned short f2bf(float f) {
    unsigned int x = __builtin_bit_cast(unsigned int, f);
    x += 0x7fffu + ((x >> 16) & 1u);
    return (unsigned short)(x >> 16);
}

__device__ __forceinline__ void gll16(const void* g, void* l) {
    __builtin_amdgcn_global_load_lds(
        (const __attribute__((address_space(1))) unsigned int*)g,
        (__attribute__((address_space(3))) unsigned int*)l, 16, 0, 0);
}

// fp8 feature layout (bytes): feat[bh][rb][cell:24][row:64][16 fp8]
// fp8 GEMM row layout (1024 fp8/row), granule-permuted per 128-byte K-step:
//   k = kstep*128 + kk*32 + lg*8 + e  <->  byte = kstep*128 + (lg*2+(kk>>1))*16 + (kk&1)*8 + e

// ---------------------------------------------------------------------------
// f32->bf16 converts: mems+h -> cbf, Wq/Wo -> bf16 scratch
// ---------------------------------------------------------------------------
__global__ __launch_bounds__(256)
void cvt_all_kernel(const float* __restrict__ h, const float* __restrict__ mems,
                    const float* __restrict__ Wq, const float* __restrict__ Wo,
                    unsigned short* __restrict__ cbf, unsigned short* __restrict__ wqb,
                    unsigned short* __restrict__ wob)
{
    int blk = blockIdx.x;
    const float* src; unsigned short* dst; int base;
    if (blk < 4096)       { src = mems; dst = cbf;           base = blk; }
    else if (blk < 8192)  { src = h;    dst = cbf + 4194304; base = blk - 4096; }
    else if (blk < 9216)  { src = Wq;   dst = wqb;           base = blk - 8192; }
    else                  { src = Wo;   dst = wob;           base = blk - 9216; }
    int i = (base * 256 + threadIdx.x) * 4;
    v4f v = *(const v4f*)(src + i);
    unsigned int p0, p1;
    asm("v_cvt_pk_bf16_f32 %0, %1, %2" : "=v"(p0) : "v"(v[0]), "v"(v[1]));
    asm("v_cvt_pk_bf16_f32 %0, %1, %2" : "=v"(p1) : "v"(v[2]), "v"(v[3]));
    uint2 u; u.x = p0; u.y = p1;
    *(uint2*)(dst + i) = u;
}

// ---------------------------------------------------------------------------
// f32 -> fp8 (e4m3) converts for the kv GEMM: c (mems+h rows) and Wkv (x32).
// Output granule-permuted (see layout comment). 8 elements/thread.
// ---------------------------------------------------------------------------
__global__ __launch_bounds__(256)
void cvt_fp8_kernel(const float* __restrict__ h, const float* __restrict__ mems,
                    const float* __restrict__ Wkv,
                    unsigned char* __restrict__ c8, unsigned char* __restrict__ w8)
{
    int tid = blockIdx.x * 256 + threadIdx.x;
    const float* src; unsigned char* dstrow; float scale; int row, k0;
    if (tid < 1048576) {               // c: 8192 rows x 1024
        int base = tid * 8; row = base >> 10; k0 = base & 1023;
        src = (row < 4096) ? (mems + (size_t)row * 1024)
                           : (h + (size_t)(row - 4096) * 1024);
        dstrow = c8 + (size_t)row * 1024; scale = 1.f;
    } else {                           // Wkv: 2048 rows x 1024, x32
        int t2 = tid - 1048576; int base = t2 * 8; row = base >> 10; k0 = base & 1023;
        src = Wkv + (size_t)row * 1024; dstrow = w8 + (size_t)row * 1024; scale = 32.f;
    }
    v4f a = *(const v4f*)(src + k0);
    v4f b = *(const v4f*)(src + k0 + 4);
    int v0 = __builtin_amdgcn_cvt_pk_fp8_f32(a[0]*scale, a[1]*scale, 0, false);
    v0     = __builtin_amdgcn_cvt_pk_fp8_f32(a[2]*scale, a[3]*scale, v0, true);
    int v1 = __builtin_amdgcn_cvt_pk_fp8_f32(b[0]*scale, b[1]*scale, 0, false);
    v1     = __builtin_amdgcn_cvt_pk_fp8_f32(b[2]*scale, b[3]*scale, v1, true);
    int kk = (k0 & 127) >> 5;
    int lg = (k0 & 31) >> 3;
    uint2 st; st.x = (unsigned int)v0; st.y = (unsigned int)v1;
    *(uint2*)(dstrow + (k0 & ~127) + (lg * 2 + (kk >> 1)) * 16 + (kk & 1) * 8) = st;
}

// ---------------------------------------------------------------------------
// fp8 MFMA GEMM for kv-proj: 128x128 tile, BK=128, 4 waves (64x64 each).
// LDS 32KB (16KB A + 16KB B, single buffer, 8 K-steps). Rows 128B with
// granule swizzle g^(row&7): staging via gll16 (linear dest, pre-swizzled
// source), frag reads b128 conflict-free (8 dwords/bank uniform).
// Wkv was pre-scaled x32 -> epilogue x1/32. cols<1024 -> outK, else outV.
// ---------------------------------------------------------------------------
__global__ __launch_bounds__(256)
void mmfp8_kernel(const unsigned char* __restrict__ A8,
                  const unsigned char* __restrict__ B8,
                  unsigned short* __restrict__ outK,
                  unsigned short* __restrict__ outV)
{
    __shared__ unsigned char As[128 * 128];   // 16KB
    __shared__ unsigned char Bs[128 * 128];   // 16KB

    const int t  = threadIdx.x;
    const int w  = t >> 6;
    const int l  = t & 63;
    const int lj = l & 15;
    const int lg = l >> 4;
    const int m0 = blockIdx.x * 128;
    const int n0 = blockIdx.y * 128;
    const int wr = w >> 1, wc = w & 1;

    const int lrow8 = l >> 3;                 // 0..7
    const int gsw   = (l & 7) ^ lrow8;        // source granule for chunkpos l&7

    v4f acc[4][4] = {};

    for (int s = 0; s < 8; ++s) {
        __syncthreads();
        #pragma unroll
        for (int u = 0; u < 4; ++u) {
            int i  = w * 4 + u;               // 0..15, 8 rows each
            int so = (i * 8 + lrow8) * 1024 + s * 128 + gsw * 16;
            gll16(A8 + (size_t)m0 * 1024 + so, (char*)As + i * 1024 + l * 16);
            gll16(B8 + (size_t)n0 * 1024 + so, (char*)Bs + i * 1024 + l * 16);
        }
        __syncthreads();

        lx2 a2[4][2], b2[4][2];
        #pragma unroll
        for (int m = 0; m < 4; ++m) {
            int row = wr * 64 + m * 16 + lj;
            #pragma unroll
            for (int gp = 0; gp < 2; ++gp) {
                int gr = lg * 2 + gp;
                a2[m][gp] = *(const lx2*)(As + row * 128 + ((gr ^ (row & 7)) * 16));
            }
        }
        #pragma unroll
        for (int nn = 0; nn < 4; ++nn) {
            int row = wc * 64 + nn * 16 + lj;
            #pragma unroll
            for (int gp = 0; gp < 2; ++gp) {
                int gr = lg * 2 + gp;
                b2[nn][gp] = *(const lx2*)(Bs + row * 128 + ((gr ^ (row & 7)) * 16));
            }
        }
        __builtin_amdgcn_s_setprio(1);
        #pragma unroll
        for (int kk = 0; kk < 4; ++kk) {
            #pragma unroll
            for (int m = 0; m < 4; ++m)
                #pragma unroll
                for (int nn = 0; nn < 4; ++nn)
                    acc[m][nn] = __builtin_amdgcn_mfma_f32_16x16x32_fp8_fp8(
                                     a2[m][kk >> 1][kk & 1], b2[nn][kk >> 1][kk & 1],
                                     acc[m][nn], 0, 0, 0);
        }
        __builtin_amdgcn_s_setprio(0);
    }

    #pragma unroll
    for (int m = 0; m < 4; ++m) {
        #pragma unroll
        for (int rr = 0; rr < 4; ++rr) {
            int row = m0 + wr * 64 + m * 16 + 4 * lg + rr;
            #pragma unroll
            for (int nn = 0; nn < 4; ++nn) {
                int col = n0 + wc * 64 + nn * 16 + lj;
                float v = acc[m][nn][rr] * 0.03125f;   // undo Wkv x32
                if (n0 < 1024) outK[(size_t)row * 1024 + col] = f2bf(v);
                else           outV[(size_t)row * 1024 + (col - 1024)] = f2bf(v);
            }
        }
    }
}

// ---------------------------------------------------------------------------
// Pure bf16 MFMA GEMM, 128x128 tile, BK=64, 4 waves.
// MODE 0: out = q_raw bf16; MODE 2: xo f32 = C + hres
// ---------------------------------------------------------------------------
template<int MODE>
__global__ __launch_bounds__(256)
void mm128_kernel(const unsigned short* __restrict__ Abf,
                  const unsigned short* __restrict__ Bbf,
                  const float* __restrict__ hres,
                  unsigned short* __restrict__ outK,
                  float* __restrict__ xo)
{
    __shared__ unsigned short As[128 * 64];
    __shared__ unsigned short Bs[128 * 64];

    const int t  = threadIdx.x;
    const int w  = t >> 6;
    const int l  = t & 63;
    const int lj = l & 15;
    const int lg = l >> 4;
    const int m0 = blockIdx.x * 128;
    const int n0 = blockIdx.y * 128;
    const int wr = w >> 1, wc = w & 1;
    const int rsub = l >> 3;
    const int csw  = ((l & 7) ^ rsub) * 16;

    v4f acc[4][4] = {};

    for (int s = 0; s < 16; ++s) {
        const int k0b = s * 128;
        __syncthreads();
        #pragma unroll
        for (int u = 0; u < 4; ++u) {
            int ra = w * 32 + u * 8;
            gll16((const char*)Abf + (size_t)(m0 + ra + rsub) * 2048 + k0b + csw,
                  (char*)As + ra * 128);
            gll16((const char*)Bbf + (size_t)(n0 + ra + rsub) * 2048 + k0b + csw,
                  (char*)Bs + ra * 128);
        }
        __syncthreads();
        #pragma unroll
        for (int ks = 0; ks < 2; ++ks) {
            bf16x8 af[4], bfr[4];
            #pragma unroll
            for (int m = 0; m < 4; ++m) {
                int row = wr * 64 + m * 16 + lj;
                int c = ks * 4 + lg;
                af[m] = *(const bf16x8*)((const char*)As + row * 128 +
                                         ((c ^ (row & 7)) * 16));
            }
            #pragma unroll
            for (int nn = 0; nn < 4; ++nn) {
                int row = wc * 64 + nn * 16 + lj;
                int c = ks * 4 + lg;
                bfr[nn] = *(const bf16x8*)((const char*)Bs + row * 128 +
                                           ((c ^ (row & 7)) * 16));
            }
            #pragma unroll
            for (int m = 0; m < 4; ++m)
                #pragma unroll
                for (int nn = 0; nn < 4; ++nn)
                    acc[m][nn] = __builtin_amdgcn_mfma_f32_16x16x32_bf16(
                                     af[m], bfr[nn], acc[m][nn], 0, 0, 0);
        }
    }

    #pragma unroll
    for (int m = 0; m < 4; ++m) {
        #pragma unroll
        for (int rr = 0; rr < 4; ++rr) {
            int row = m0 + wr * 64 + m * 16 + 4 * lg + rr;
            #pragma unroll
            for (int nn = 0; nn < 4; ++nn) {
                int col = n0 + wc * 64 + nn * 16 + lj;
                float v = acc[m][nn][rr];
                if constexpr (MODE == 2) {
                    xo[(size_t)row * 1024 + col] = v + hres[(size_t)row * 1024 + col];
                } else {
                    outK[(size_t)row * 1024 + col] = f2bf(v);
                }
            }
        }
    }
}

// ---------------------------------------------------------------------------
// DPFP feature kernel — LDS-resident g, fp8 (e4m3) output, chunk-blocked:
//   feat[bh][rb][cell24][row64][16 fp8], stores 1KB contiguous per instr.
// ---------------------------------------------------------------------------
__device__ __forceinline__ float gld(const unsigned short* gr, int idx) {
    return __builtin_bit_cast(float, ((unsigned int)gr[idx]) << 16);
}

template<int FBASE>
__device__ __forceinline__ void dpfp_half8(const unsigned short* __restrict__ gr,
                                           unsigned char* __restrict__ drow)
{
    #pragma unroll
    for (int c = 0; c < 12; ++c) {
        unsigned int w4[4];
        #pragma unroll
        for (int q4 = 0; q4 < 4; ++q4) {
            float p[4];
            #pragma unroll
            for (int e = 0; e < 4; ++e) {
                const int f  = FBASE + c * 16 + q4 * 4 + e;
                const int r  = (f >> 7) + 1;
                const int tt = f & 127;
                const int uu = (tt - r) & 127;
                p[e] = gld(gr, tt) * gld(gr, uu);
            }
            int v = __builtin_amdgcn_cvt_pk_fp8_f32(p[0], p[1], 0, false);
            v     = __builtin_amdgcn_cvt_pk_fp8_f32(p[2], p[3], v, true);
            w4[q4] = (unsigned int)v;
        }
        u32x4 st = {w4[0], w4[1], w4[2], w4[3]};
        *(u32x4*)(drow + c * 1024) = st;
    }
}

__global__ __launch_bounds__(256)
void dpfp_kernel(const unsigned short* __restrict__ qraw,
                 const unsigned short* __restrict__ kraw,
                 unsigned char* __restrict__ qf, unsigned char* __restrict__ kf)
{
    __shared__ unsigned short G[128 * 138];

    const int t   = threadIdx.x;
    const int blk = blockIdx.x;

    const unsigned short* src; unsigned char* dst; int b, hh, seq0;
    if (blk < 512) {
        int bh = blk >> 2, ig = blk & 3;
        b = bh >> 4; hh = bh & 15; seq0 = ig * 128;
        src = qraw; dst = qf + (size_t)bh * 196608;
    } else {
        int blk2 = blk - 512;
        int bh = blk2 >> 3, jg = blk2 & 7;
        b = bh >> 4; hh = bh & 15; seq0 = jg * 128;
        src = kraw; dst = kf + (size_t)bh * 393216;
    }

    #pragma unroll
    for (int p = 0; p < 4; ++p) {
        int u   = p * 256 + t;
        int row = u >> 3;
        int c0  = (u & 7) * 8;
        u32x4 x = *(const u32x4*)(src + ((size_t)(seq0 + row) * 8 + b) * 1024 +
                                  hh * 64 + c0);
        char* gbase = (char*)G + row * 276 + c0 * 2;
        #pragma unroll
        for (int k = 0; k < 4; ++k) {
            unsigned int xk = x[k];
            float x0 = __builtin_bit_cast(float, xk << 16);
            float x1 = __builtin_bit_cast(float, xk & 0xffff0000u);
            float a0 = fmaxf(x0, 0.f), a1 = fmaxf(x1, 0.f);
            float b0 = fmaxf(-x0, 0.f), b1 = fmaxf(-x1, 0.f);
            unsigned int lo, hig;
            asm("v_cvt_pk_bf16_f32 %0, %1, %2" : "=v"(lo) : "v"(a0), "v"(a1));
            asm("v_cvt_pk_bf16_f32 %0, %1, %2" : "=v"(hig) : "v"(b0), "v"(b1));
            *(unsigned int*)(gbase + k * 4)       = lo;
            *(unsigned int*)(gbase + 128 + k * 4) = hig;
        }
    }
    __syncthreads();

    const int w    = t >> 6;
    const int l    = t & 63;
    const int rowc = (w >> 1) * 64 + l;
    const int hs   = w & 1;
    const unsigned short* gr = G + rowc * 138;
    const int seq = seq0 + rowc;
    unsigned char* drow = dst + (size_t)(seq >> 6) * 24576 + (seq & 63) * 16 +
                          hs * 12288;
    if (hs == 0) dpfp_half8<0>(gr, drow);
    else         dpfp_half8<192>(gr, drow);
}

// ---------------------------------------------------------------------------
// V transpose: v_raw [8192=(j,b)][1024=(h,d)] bf16 -> vt [b,h][d][KLEN] bf16.
// ---------------------------------------------------------------------------
__global__ __launch_bounds__(256)
void vtrans_kernel(const unsigned short* __restrict__ vraw,
                   unsigned short* __restrict__ vt)
{
    __shared__ unsigned short S[256][72];
    const int t  = threadIdx.x;
    const int jc = blockIdx.x, hh = blockIdx.y, b = blockIdx.z;
    const unsigned short* src = vraw + (size_t)((jc * 256 + t) * 8 + b) * 1024 + hh * 64;
    #pragma unroll
    for (int c = 0; c < 8; ++c)
        *(u32x4*)&S[t][c * 8] = *(const u32x4*)(src + c * 8);
    __syncthreads();
    const int d = t >> 2, qq = t & 3;
    unsigned short* dst = vt + ((size_t)(b * NH + hh) * HD + d) * KLEN + jc * 256 + qq * 64;
    #pragma unroll
    for (int c8 = 0; c8 < 8; ++c8) {
        u16x8 o;
        #pragma unroll
        for (int e = 0; e < 8; ++e) o[e] = S[qq * 64 + c8 * 8 + e][d];
        *(u16x8*)(dst + c8 * 8) = o;
    }
}

// ---------------------------------------------------------------------------
// MFMA attention v4: fp8 K/Q (32x32x16_fp8_fp8 QK^T), swapped QK^T, in-reg P
// (cvt_pk + permlane32_swap), bf16 PV. K staged LINEAR. KVBLK=64, setprio
// around MFMA clusters. LDS ~33KB.
// ---------------------------------------------------------------------------
__global__ __launch_bounds__(256, 2)
void attn_mfma_kernel(const unsigned char* __restrict__ qf,
                      const unsigned char* __restrict__ kf,
                      const unsigned short* __restrict__ vt,
                      unsigned short* __restrict__ avec)
{
    __shared__ unsigned char Ks[64 * 384];    // 24KB fp8: [cell24][row64][16B]
    __shared__ unsigned short Vs[64 * 64];    // 8KB bf16: rows(d) 128B, swizzled
    __shared__ float Ds[4][32];

    const int t  = threadIdx.x;
    const int w  = t >> 6;
    const int l  = t & 63;
    const int li = l & 31;
    const int hi = l >> 5;

    const int bid = blockIdx.x;
    const int it  = (bid >> 3) & 3;
    const int P   = ((bid >> 5) << 3) + (bid & 7);
    const int n   = P & 15;
    const int b   = P >> 4;

    const unsigned char* qpan = qf + (size_t)P * 196608;
    const unsigned char* kpan = kf + (size_t)P * 393216;
    const char* vpan = (const char*)(vt + (size_t)P * HD * KLEN);

    int voff[2];
    #pragma unroll
    for (int uu = 0; uu < 2; ++uu) {
        int s  = (w * 2 + uu) * 64 + l;
        int d  = s >> 3;
        int cl = s & 7;
        int cg = cl ^ (d & 7);
        voff[uu] = d * (KLEN * 2) + cg * 16;
    }

    long qfr[24];
    {
        const unsigned char* qb = qpan + (size_t)(it * 2 + (w >> 1)) * 24576 +
                                  ((w & 1) * 32 + li) * 16 + hi * 8;
        #pragma unroll
        for (int ks = 0; ks < 24; ++ks)
            qfr[ks] = *(const long*)(qb + ks * 1024);
    }

    f32x16 num[2] = {};
    float den_acc = 0.f;

    const int ig         = it * 128 + w * 32 + li;
    const int my_jt_end  = 2 * it + 8 + (w >> 1);
    const int jt_blk_end = 2 * it + 9;

    for (int jt = 0; jt <= jt_blk_end; ++jt) {
        __syncthreads();
        const unsigned char* ktile = kpan + (size_t)jt * 24576;
        #pragma unroll
        for (int u = 0; u < 6; ++u)
            gll16(ktile + (w * 6 + u) * 1024 + l * 16, Ks + (w * 6 + u) * 1024);
        const char* vtile = vpan + jt * 128;
        #pragma unroll
        for (int uu = 0; uu < 2; ++uu)
            gll16(vtile + voff[uu], (char*)Vs + (w * 2 + uu) * 1024);
        __syncthreads();

        if (jt > my_jt_end) continue;

        f32x16 sacc0 = {};
        f32x16 sacc1 = {};
        __builtin_amdgcn_s_setprio(1);
        #pragma unroll
        for (int ks = 0; ks < 24; ++ks) {
            long k0 = *(const long*)(Ks + ks * 1024 + li * 16 + hi * 8);
            long k1 = *(const long*)(Ks + ks * 1024 + (32 + li) * 16 + hi * 8);
            sacc0 = __builtin_amdgcn_mfma_f32_32x32x16_fp8_fp8(k0, qfr[ks], sacc0, 0, 0, 0);
            sacc1 = __builtin_amdgcn_mfma_f32_32x32x16_fp8_fp8(k1, qfr[ks], sacc1, 0, 0, 0);
        }
        __builtin_amdgcn_s_setprio(0);

        if (jt == my_jt_end) {
            const int joff = jt * 64 - MLEN + 4 * hi;
            #pragma unroll
            for (int reg = 0; reg < 16; ++reg) {
                int jr = (reg & 3) + 8 * (reg >> 2);
                if (joff + jr > ig)      sacc0[reg] = 0.f;
                if (joff + 32 + jr > ig) sacc1[reg] = 0.f;
            }
        }
        {
            float dpart = 0.f;
            #pragma unroll
            for (int reg = 0; reg < 16; ++reg) dpart += sacc0[reg] + sacc1[reg];
            den_acc += dpart + __shfl_xor(dpart, 32);
        }

        #pragma unroll
        for (int jf = 0; jf < 2; ++jf) {
            const f32x16 sc = jf ? sacc1 : sacc0;
            unsigned int c01, c23, c45, c67, c89, cab, ccd, cef;
            asm("v_cvt_pk_bf16_f32 %0, %1, %2" : "=v"(c01) : "v"(sc[0]),  "v"(sc[1]));
            asm("v_cvt_pk_bf16_f32 %0, %1, %2" : "=v"(c23) : "v"(sc[2]),  "v"(sc[3]));
            asm("v_cvt_pk_bf16_f32 %0, %1, %2" : "=v"(c45) : "v"(sc[4]),  "v"(sc[5]));
            asm("v_cvt_pk_bf16_f32 %0, %1, %2" : "=v"(c67) : "v"(sc[6]),  "v"(sc[7]));
            asm("v_cvt_pk_bf16_f32 %0, %1, %2" : "=v"(c89) : "v"(sc[8]),  "v"(sc[9]));
            asm("v_cvt_pk_bf16_f32 %0, %1, %2" : "=v"(cab) : "v"(sc[10]), "v"(sc[11]));
            asm("v_cvt_pk_bf16_f32 %0, %1, %2" : "=v"(ccd) : "v"(sc[12]), "v"(sc[13]));
            asm("v_cvt_pk_bf16_f32 %0, %1, %2" : "=v"(cef) : "v"(sc[14]), "v"(sc[15]));
            u32x2 r0 = __builtin_amdgcn_permlane32_swap(c01, c45, false, false);
            u32x2 r1 = __builtin_amdgcn_permlane32_swap(c23, c67, false, false);
            u32x2 r2 = __builtin_amdgcn_permlane32_swap(c89, ccd, false, false);
            u32x2 r3 = __builtin_amdgcn_permlane32_swap(cab, cef, false, false);
            u32x4 pw0 = {r0.x, r1.x, r0.y, r1.y};
            u32x4 pw1 = {r2.x, r3.x, r2.y, r3.y};
            bf16x8 pa0 = __builtin_bit_cast(bf16x8, pw0);
            bf16x8 pa1 = __builtin_bit_cast(bf16x8, pw1);
            __builtin_amdgcn_s_setprio(1);
            #pragma unroll
            for (int dd = 0; dd < 2; ++dd) {
                int d = dd * 32 + li;
                {
                    int cs = (jf * 4 + hi) ^ (d & 7);
                    bf16x8 vb = *(const bf16x8*)((const char*)Vs + d * 128 + cs * 16);
                    num[dd] = __builtin_amdgcn_mfma_f32_32x32x16_bf16(pa0, vb, num[dd], 0, 0, 0);
                }
                {
                    int cs = (jf * 4 + 2 + hi) ^ (d & 7);
                    bf16x8 vb = *(const bf16x8*)((const char*)Vs + d * 128 + cs * 16);
                    num[dd] = __builtin_amdgcn_mfma_f32_32x32x16_bf16(pa1, vb, num[dd], 0, 0, 0);
                }
            }
            __builtin_amdgcn_s_setprio(0);
        }
    }

    if (l < 32) Ds[w][l] = den_acc;
    #pragma unroll
    for (int reg = 0; reg < 16; ++reg) {
        int i_loc = (reg & 3) + 8 * (reg >> 2) + 4 * hi;
        float dv = Ds[w][i_loc];
        float minv = ATT_SCALE / (dv * ATT_SCALE + EPSV);
        int ig2 = it * 128 + w * 32 + i_loc;
        unsigned short* orow = avec + ((size_t)ig2 * BB + b) * DMODEL + n * HD;
        orow[li]      = f2bf(num[0][reg] * minv);
        orow[32 + li] = f2bf(num[1][reg] * minv);
    }
}

// ---------------------------------------------------------------------------
// Row LayerNorm over DM=1024.
// ---------------------------------------------------------------------------
__global__ __launch_bounds__(256)
void ln_kernel(const float* __restrict__ x, const float* __restrict__ gamma,
               const float* __restrict__ beta, float* __restrict__ out)
{
    const int row = blockIdx.x;
    const int t = threadIdx.x;
    const float* xr = x + (size_t)row * DMODEL;
    v4f xv = *(const v4f*)(xr + (t << 2));
    float s1 = xv[0] + xv[1] + xv[2] + xv[3];
    float s2 = xv[0]*xv[0] + xv[1]*xv[1] + xv[2]*xv[2] + xv[3]*xv[3];
    #pragma unroll
    for (int off = 32; off > 0; off >>= 1) {
        s1 += __shfl_down(s1, off);
        s2 += __shfl_down(s2, off);
    }
    __shared__ float red[2][4];
    __shared__ float mv[2];
    const int wave = t >> 6;
    if ((t & 63) == 0) { red[0][wave] = s1; red[1][wave] = s2; }
    __syncthreads();
    if (t == 0) {
        float a = red[0][0] + red[0][1] + red[0][2] + red[0][3];
        float q = red[1][0] + red[1][1] + red[1][2] + red[1][3];
        float mu  = a * (1.f / DMODEL);
        float var = q * (1.f / DMODEL) - mu * mu;
        mv[0] = mu;
        mv[1] = rsqrtf(var + EPSV);
    }
    __syncthreads();
    float mu = mv[0], rs = mv[1];
    v4f gv = *(const v4f*)(gamma + (t << 2));
    v4f bv = *(const v4f*)(beta + (t << 2));
    v4f o;
    #pragma unroll
    for (int e = 0; e < 4; ++e) o[e] = (xv[e] - mu) * rs * gv[e] + bv[e];
    *(v4f*)(out + (size_t)row * DMODEL + (t << 2)) = o;
}

extern "C" void kernel_launch(void* const* d_in, const int* in_sizes, int n_in,
                              void* d_out, int out_size, void* d_ws, size_t ws_size,
                              hipStream_t stream)
{
    const float* h     = (const float*)d_in[0];
    const float* mems  = (const float*)d_in[1];
    const float* Wq    = (const float*)d_in[2];
    const float* Wkv   = (const float*)d_in[3];
    const float* Wo    = (const float*)d_in[4];
    const float* gamma = (const float*)d_in[5];
    const float* beta  = (const float*)d_in[6];
    // d_in[7] = attn_mask: causal structure computed analytically, ignored.

    char* ws = (char*)d_ws;
    unsigned char* qf    = (unsigned char*)(ws);              // [0, 25.17M) fp8 feats
    unsigned char* kf    = (unsigned char*)(ws + 25165824);   // [25.17M, 75.50M) fp8
    unsigned char* c8    = (unsigned char*)(ws + 75497472);   // 8.39M fp8 (kv GEMM A)
    unsigned char* w8    = (unsigned char*)(ws + 83886080);   // 2.10M fp8 (kv GEMM B)
    unsigned short* kraw = (unsigned short*)(ws + 150994944); // 16.78M bf16
    unsigned short* vt   = kraw;                              // overlay after dpfp
    unsigned short* vraw = (unsigned short*)(ws + 167772160); // 16.78M
    unsigned short* cbf  = (unsigned short*)(ws + 184549376); // 16.78M
    unsigned short* qraw = cbf;                               // overlay mems-half after kv
    unsigned short* avec = cbf;                               // overlay after dpfp
    float* xws = (float*)(ws);                                // overlay qf after attn

    unsigned short* wqb  = (unsigned short*)d_out;            // bf16 weights in d_out
    unsigned short* wob  = wqb + 1048576;

    cvt_all_kernel<<<10240, 256, 0, stream>>>(h, mems, Wq, Wo, cbf, wqb, wob);
    cvt_fp8_kernel<<<5120, 256, 0, stream>>>(h, mems, Wkv, c8, w8);
    mmfp8_kernel<<<dim3(64, 16), 256, 0, stream>>>(c8, w8, kraw, vraw);
    mm128_kernel<0><<<dim3(32, 8), 256, 0, stream>>>(cbf + 4194304, wqb, nullptr, qraw, nullptr);
    dpfp_kernel<<<1536, 256, 0, stream>>>(qraw, kraw, qf, kf);
    vtrans_kernel<<<dim3(4, 16, 8), 256, 0, stream>>>(vraw, vt);
    attn_mfma_kernel<<<512, 256, 0, stream>>>(qf, kf, vt, avec);
    mm128_kernel<2><<<dim3(32, 8), 256, 0, stream>>>(avec, wob, h, nullptr, xws);
    ln_kernel<<<4096, 256, 0, stream>>>(xws, gamma, beta, (float*)d_out);
}